// Round 8
// baseline (6428.606 us; speedup 1.0000x reference)
//
#include <hip/hip_runtime.h>
#include <math.h>

#define BB 64
#define TT 128
#define SS 256
#define HHH 1024
#define SCANBLK 64

typedef unsigned short u16;
typedef unsigned int u32;
typedef unsigned long long u64t;
typedef __bf16 bf16x8 __attribute__((ext_vector_type(8)));
typedef float f32x4 __attribute__((ext_vector_type(4)));
typedef u16 u16x8 __attribute__((ext_vector_type(8)));

__device__ __forceinline__ float sigmoidf_(float x) { return 1.0f / (1.0f + expf(-x)); }
__device__ __forceinline__ u16 f2bf(float f) {
    __bf16 h = (__bf16)f;
    return __builtin_bit_cast(u16, h);
}
__device__ __forceinline__ float b2f(u16 u) {
    return __builtin_bit_cast(float, (u32)u << 16);
}
template <typename OT>
__device__ __forceinline__ void stout(OT* p, float v) {
    if constexpr (sizeof(OT) == 2) *p = f2bf(v); else *p = v;
}
__device__ __forceinline__ u64t aload(const u64t* p) {
    return __hip_atomic_load(p, __ATOMIC_RELAXED, __HIP_MEMORY_SCOPE_AGENT);
}
__device__ __forceinline__ void astore(u64t* p, u64t v) {
    __hip_atomic_store(p, v, __ATOMIC_RELAXED, __HIP_MEMORY_SCOPE_AGENT);
}

// ---------------------------------------------------------------------------
// fp32 → bf16 elementwise
// ---------------------------------------------------------------------------
__global__ __launch_bounds__(256) void f32_to_bf16(const float* __restrict__ in,
                                                   u16* __restrict__ out, long n) {
    long i = ((long)blockIdx.x * 256 + threadIdx.x) * 8;
    float4 a = *(const float4*)(in + i);
    float4 b = *(const float4*)(in + i + 4);
    u16x8 o;
    o[0] = f2bf(a.x); o[1] = f2bf(a.y); o[2] = f2bf(a.z); o[3] = f2bf(a.w);
    o[4] = f2bf(b.x); o[5] = f2bf(b.y); o[6] = f2bf(b.z); o[7] = f2bf(b.w);
    *(u16x8*)(out + i) = o;
}

// ---------------------------------------------------------------------------
// W_hh [row=g*1024+j][1024] fp32 -> Whi/Wlo bf16 [row'=j*4+g][1024]
// ---------------------------------------------------------------------------
__global__ __launch_bounds__(256) void split_whh(const float* __restrict__ W,
                                                 u16* __restrict__ hi,
                                                 u16* __restrict__ lo) {
    const int row = blockIdx.x;
    const int g = row >> 10, j = row & 1023;
    const int dst = (j << 2) | g;
    const int k4 = threadIdx.x << 2;
    float4 v = *(const float4*)(W + (size_t)row * 1024 + k4);
    u16 h0 = f2bf(v.x), h1 = f2bf(v.y), h2 = f2bf(v.z), h3 = f2bf(v.w);
    ushort4 hv = {h0, h1, h2, h3};
    ushort4 lv = {f2bf(v.x - b2f(h0)), f2bf(v.y - b2f(h1)),
                  f2bf(v.z - b2f(h2)), f2bf(v.w - b2f(h3))};
    *(ushort4*)(hi + (size_t)dst * 1024 + k4) = hv;
    *(ushort4*)(lo + (size_t)dst * 1024 + k4) = lv;
}

// ---------------------------------------------------------------------------
// h0 [64 b][1024 j] fp32 -> packed (hi | lo<<16) u32, same [b][j] layout
// ---------------------------------------------------------------------------
__global__ __launch_bounds__(256) void h0_pack(const float* __restrict__ h0,
                                               u32* __restrict__ out) {
    int i = blockIdx.x * 256 + threadIdx.x;
    float v = h0[i];
    u16 hi = f2bf(v);
    u16 lo = f2bf(v - b2f(hi));
    out[i] = (u32)hi | ((u32)lo << 16);
}

// ---------------------------------------------------------------------------
// MFMA bf16 GEMM (A@B^T). XGT mode: logical A row r=t*64+b (phys (r&63)*128+(r>>6));
// C written fp32 to xgt[t][r'=j*4+g][b] with (b_ih+b_hh) folded.
// ---------------------------------------------------------------------------
template <bool TANH, bool XGT, typename OT>
__global__ __launch_bounds__(256) void gemm_mfma_bt(
    const u16* __restrict__ A0, const u16* __restrict__ A1,
    const u16* __restrict__ B, OT* __restrict__ C,
    int M, int N, int K, int KA0,
    const float* __restrict__ bias0, const float* __restrict__ bias1)
{
    __shared__ uint4 As4[512];
    __shared__ uint4 Bs4[512];
    u16* As = (u16*)As4;
    u16* Bs = (u16*)Bs4;
    const int tid = threadIdx.x;
    const int l = tid & 63;
    const int w = tid >> 6;
    const int wm = w >> 1, wn = w & 1;
    const int tc = l & 15, tr8 = (l >> 4) << 3;
    const int m0 = blockIdx.y << 7, n0 = blockIdx.x << 7;
    f32x4 acc[4][4] = {};

    for (int k0 = 0; k0 < K; k0 += 32) {
        const u16* Ap = (k0 < KA0) ? A0 : A1;
        const int koff = (k0 < KA0) ? k0 : k0 - KA0;
#pragma unroll
        for (int r = 0; r < 2; ++r) {
            int u = tid + (r << 8);
            int row = u >> 2, q = u & 3;
            size_t arow;
            if (XGT) {
                int rr = m0 + row;
                arow = (size_t)((rr & 63) * 128 + (rr >> 6));
            } else {
                arow = (size_t)(m0 + row);
            }
            As4[u] = *(const uint4*)(Ap + arow * KA0 + koff + (q << 3));
            Bs4[u] = *(const uint4*)(B + (size_t)(n0 + row) * K + k0 + (q << 3));
        }
        __syncthreads();
        bf16x8 bfr[4];
#pragma unroll
        for (int j = 0; j < 4; ++j)
            bfr[j] = *(const bf16x8*)(Bs + ((wn << 6) + (j << 4) + tc) * 32 + tr8);
#pragma unroll
        for (int i = 0; i < 4; ++i) {
            bf16x8 af = *(const bf16x8*)(As + ((wm << 6) + (i << 4) + tc) * 32 + tr8);
#pragma unroll
            for (int j = 0; j < 4; ++j)
                acc[i][j] = __builtin_amdgcn_mfma_f32_16x16x32_bf16(af, bfr[j], acc[i][j], 0, 0, 0);
        }
        __syncthreads();
    }
#pragma unroll
    for (int j = 0; j < 4; ++j) {
        const int col = n0 + (wn << 6) + (j << 4) + tc;
        const float bias = XGT ? (bias0[col] + bias1[col]) : 0.0f;
#pragma unroll
        for (int i = 0; i < 4; ++i) {
#pragma unroll
            for (int v = 0; v < 4; ++v) {
                int r = m0 + (wm << 6) + (i << 4) + ((l >> 4) << 2) + v;
                float val = acc[i][j][v];
                if (XGT) {
                    int newr = ((col & 1023) << 2) | (col >> 10);   // j*4+g
                    ((float*)C)[(size_t)(r >> 6) * 262144 + (size_t)newr * 64 + (r & 63)] = val + bias;
                } else {
                    if (TANH) val = tanhf(val);
                    stout(&C[(size_t)r * N + col], val);
                }
            }
        }
    }
}

// ---------------------------------------------------------------------------
// Persistent LSTM scan v4. 64 blocks x 512 thr (8 waves = 2/SIMD), 128 steps.
// Block owns 16 j x 4 gates = 64 W-rows for all 64 b.
// Waves = 4 b-tiles x 2 k-halves. Per step, each wave stages its (16 b x 512 j)
// h-slice from the packed global buffer into LDS windows of 64 j (2-deep
// software pipeline: lane-contiguous 8B atomic loads = full-line coalesced),
// unpacks hi/lo bf16 via v_perm, and runs the split-precision MFMAs
// (Whi@hhi + Whi@hlo + Wlo@hhi). Cross-wave reduce = only 2 k-half partials.
// h exchange via memory-side relaxed atomics (proven coherent in r6/r7);
// monotonic-counter grid barrier (proven). c lives in registers.
// ---------------------------------------------------------------------------
__global__ __launch_bounds__(512) void lstm_scan4(
    const float* __restrict__ xgt,
    const u16* __restrict__ Whi, const u16* __restrict__ Wlo,
    const float* __restrict__ c0,
    u32* __restrict__ hE, u32* __restrict__ hO,
    float* __restrict__ hT, float* __restrict__ cT,
    u16* __restrict__ lstm16, int* __restrict__ cnt)
{
    __shared__ float red[8][64][17];        // 34.8 KB: per-wave partial gates
    __shared__ u32 stg[8][2][16 * 67];      // 68.6 KB: per-wave h window dbuf
    __shared__ u32 tile[64][18];            // 4.6 KB: packed h-out tile

    const int tid = threadIdx.x;
    const int kg = tid >> 6;          // wave 0..7
    const int l = tid & 63;
    const int bt = kg & 3;            // b-tile
    const int kh = kg >> 2;           // k-half
    const int tc = l & 15, tr = l >> 4;
    const int j0 = blockIdx.x << 4;   // 16 j per block
    const int r0 = blockIdx.x << 6;   // 64 gate-rows per block
    const int khbase = kh << 9;       // 0 or 512

    const int eb = tid & 63;          // epilogue batch
    const int ej = tid >> 6;          // epilogue j (and +8)

    float cv[2];
    cv[0] = c0[(size_t)eb * 1024 + j0 + ej];
    cv[1] = c0[(size_t)eb * 1024 + j0 + ej + 8];

    for (int t = 0; t < 128; ++t) {
        const u32* hin = (t & 1) ? hO : hE;
        u32* hout = (t & 1) ? hE : hO;
        const u64t* hin64 = (const u64t*)hin;

        // xg gate values (cached; in flight through the MFMA phase)
        float xgv[2][4];
#pragma unroll
        for (int p = 0; p < 2; ++p)
#pragma unroll
            for (int g = 0; g < 4; ++g)
                xgv[p][g] = xgt[(size_t)t * 262144 +
                                (size_t)((j0 + ej + p * 8) * 4 + g) * 64 + eb];

        u64t pendA[8], pendB[8];
        auto issueTo = [&](u64t* pend, int w) {
            const int jw = khbase + (w << 6);
#pragma unroll
            for (int r = 0; r < 8; ++r) {
                int bl = (r << 1) + (l >> 5);
                pend[r] = aload(hin64 +
                    ((((size_t)(bt * 16 + bl)) << 10) + jw) / 2 + (l & 31));
            }
        };
        auto commitA = [&](int s) {
#pragma unroll
            for (int r = 0; r < 8; ++r) {
                int bl = (r << 1) + (l >> 5);
                u32* dp = &stg[kg][s][bl * 67 + ((l & 31) << 1)];
                dp[0] = (u32)pendA[r];
                dp[1] = (u32)(pendA[r] >> 32);
            }
        };
        auto commitB = [&](int s) {
#pragma unroll
            for (int r = 0; r < 8; ++r) {
                int bl = (r << 1) + (l >> 5);
                u32* dp = &stg[kg][s][bl * 67 + ((l & 31) << 1)];
                dp[0] = (u32)pendB[r];
                dp[1] = (u32)(pendB[r] >> 32);
            }
        };

        f32x4 acc[4] = {};
        auto compute = [&](int s, int w) {
#pragma unroll
            for (int half = 0; half < 2; ++half) {
                const int k = khbase + (w << 6) + (half << 5) + (tr << 3);
                u32 d[8];
#pragma unroll
                for (int m = 0; m < 8; ++m)
                    d[m] = stg[kg][s][tc * 67 + (half << 5) + (tr << 3) + m];
                union { u32 u[4]; bf16x8 v; } bh, bl2;
#pragma unroll
                for (int m = 0; m < 4; ++m) {
                    bh.u[m]  = __builtin_amdgcn_perm(d[2 * m + 1], d[2 * m], 0x05040100u);
                    bl2.u[m] = __builtin_amdgcn_perm(d[2 * m + 1], d[2 * m], 0x07060302u);
                }
#pragma unroll
                for (int rt = 0; rt < 4; ++rt) {
                    bf16x8 ah = *(const bf16x8*)(Whi + (size_t)(r0 + rt * 16 + tc) * 1024 + k);
                    bf16x8 al = *(const bf16x8*)(Wlo + (size_t)(r0 + rt * 16 + tc) * 1024 + k);
                    acc[rt] = __builtin_amdgcn_mfma_f32_16x16x32_bf16(ah, bh.v, acc[rt], 0, 0, 0);
                    acc[rt] = __builtin_amdgcn_mfma_f32_16x16x32_bf16(ah, bl2.v, acc[rt], 0, 0, 0);
                    acc[rt] = __builtin_amdgcn_mfma_f32_16x16x32_bf16(al, bh.v, acc[rt], 0, 0, 0);
                }
            }
        };

        // 8 windows, 2-deep issue pipeline, static pend selection (no scratch)
        issueTo(pendA, 0);
        commitA(0);
        issueTo(pendA, 1);
#pragma unroll
        for (int w2 = 0; w2 < 8; w2 += 2) {
            if (w2 + 2 < 8) issueTo(pendB, w2 + 2);
            compute(0, w2);
            commitA(1);                       // window w2+1 -> buf 1
            if (w2 + 3 < 8) issueTo(pendA, w2 + 3);
            compute(1, w2 + 1);
            if (w2 + 2 < 8) commitB(0);       // window w2+2 -> buf 0
        }

#pragma unroll
        for (int rt = 0; rt < 4; ++rt)
#pragma unroll
            for (int v = 0; v < 4; ++v)
                red[kg][rt * 16 + tr * 4 + v][tc] = acc[rt][v];
        __syncthreads();

        // epilogue: thread -> (b=eb, jl=ej and ej+8)
#pragma unroll
        for (int p = 0; p < 2; ++p) {
            const int jl = ej + p * 8;
            const int btb = eb >> 4, bl = eb & 15;
            float gate[4];
#pragma unroll
            for (int g = 0; g < 4; ++g) {
                int rr = jl * 4 + g;
                gate[g] = red[btb][rr][bl] + red[btb + 4][rr][bl] + xgv[p][g];
            }
            float ii = sigmoidf_(gate[0]);
            float ff = sigmoidf_(gate[1]);
            float gg = tanhf(gate[2]);
            float oo = sigmoidf_(gate[3]);
            float cn = ff * cv[p] + ii * gg;
            float hn = oo * tanhf(cn);
            cv[p] = cn;
            u16 hh = f2bf(hn);
            u16 hl = f2bf(hn - b2f(hh));
            tile[eb][jl] = (u32)hh | ((u32)hl << 16);
            if (t == 127) {
                hT[(size_t)eb * 1024 + j0 + jl] = hn;
                cT[(size_t)eb * 1024 + j0 + jl] = cn;
            }
        }
        __syncthreads();

        // coalesced h-out row stores (memory-side) + lstm_out hi extraction
        if (tid < 64) {
            u64t* o64 = (u64t*)hout + ((((size_t)tid << 10) + j0) >> 1);
            const u64t* src = (const u64t*)&tile[tid][0];
#pragma unroll
            for (int q = 0; q < 8; ++q) astore(o64 + q, src[q]);
            u32 hv[8];
#pragma unroll
            for (int m = 0; m < 8; ++m)
                hv[m] = __builtin_amdgcn_perm(tile[tid][2 * m + 1], tile[tid][2 * m], 0x05040100u);
            uint4* dst = (uint4*)(lstm16 + ((size_t)tid * 128 + t) * 1024 + j0);
            dst[0] = make_uint4(hv[0], hv[1], hv[2], hv[3]);
            dst[1] = make_uint4(hv[4], hv[5], hv[6], hv[7]);
        }

        // grid barrier (syncthreads drains vmem incl. the h-stores first)
        if (t < 127) {
            __syncthreads();
            if (tid == 0) {
                __hip_atomic_fetch_add(cnt, 1, __ATOMIC_RELAXED, __HIP_MEMORY_SCOPE_AGENT);
                const int target = SCANBLK * (t + 1);
                while (__hip_atomic_load(cnt, __ATOMIC_RELAXED, __HIP_MEMORY_SCOPE_AGENT) < target)
                    __builtin_amdgcn_s_sleep(2);
            }
            __syncthreads();
            asm volatile("" ::: "memory");
        }
    }
}

// ---------------------------------------------------------------------------
// fp32 GEMM C = A @ B^T (scores), batched via blockIdx.z.
// ---------------------------------------------------------------------------
template <int BM, int BN, int TM, int TN>
__global__ __launch_bounds__(256) void gemm_bt(
    const float* __restrict__ A, const float* __restrict__ Bm, float* __restrict__ C,
    int M, int N, int K, long sA, long sB, long sC)
{
    constexpr int BK = 16;
    __shared__ float As[BK][BM + 1];
    __shared__ float Bs[BK][BN + 1];
    const int z = blockIdx.z;
    A += (long)z * sA; Bm += (long)z * sB; C += (long)z * sC;
    const int bm = blockIdx.y * BM, bn = blockIdx.x * BN;
    const int tid = threadIdx.x;
    constexpr int TC = BN / TN;
    const int tc = tid % TC, tr = tid / TC;
    float acc[TM][TN] = {};
    for (int k0 = 0; k0 < K; k0 += BK) {
        for (int i = tid; i < BM * 4; i += 256) {
            int m = i >> 2, k4 = (i & 3) << 2;
            float4 v = *(const float4*)(A + (long)(bm + m) * K + k0 + k4);
            As[k4][m] = v.x; As[k4 + 1][m] = v.y; As[k4 + 2][m] = v.z; As[k4 + 3][m] = v.w;
        }
        for (int i = tid; i < BN * 4; i += 256) {
            int n = i >> 2, k4 = (i & 3) << 2;
            float4 v = *(const float4*)(Bm + (long)(bn + n) * K + k0 + k4);
            Bs[k4][n] = v.x; Bs[k4 + 1][n] = v.y; Bs[k4 + 2][n] = v.z; Bs[k4 + 3][n] = v.w;
        }
        __syncthreads();
#pragma unroll
        for (int kk = 0; kk < BK; ++kk) {
            float a[TM], b[TN];
#pragma unroll
            for (int i = 0; i < TM; i++) a[i] = As[kk][tr * TM + i];
#pragma unroll
            for (int j = 0; j < TN; j++) b[j] = Bs[kk][tc * TN + j];
#pragma unroll
            for (int i = 0; i < TM; i++)
#pragma unroll
                for (int j = 0; j < TN; j++) acc[i][j] += a[i] * b[j];
        }
        __syncthreads();
    }
#pragma unroll
    for (int i = 0; i < TM; i++) {
        int m = bm + tr * TM + i;
#pragma unroll
        for (int j = 0; j < TN; j++) {
            int n = bn + tc * TN + j;
            C[(long)m * N + n] = acc[i][j];
        }
    }
}

// ---------------------------------------------------------------------------
// fp32 GEMM C = A @ B (context = attn @ ctx), OT output.
// ---------------------------------------------------------------------------
template <int BM, int BN, int TM, int TN, typename OT>
__global__ __launch_bounds__(256) void gemm_bn(
    const float* __restrict__ A, const float* __restrict__ Bm, OT* __restrict__ C,
    int M, int N, int K, long sA, long sB, long sC)
{
    constexpr int BK = 16;
    __shared__ float As[BK][BM + 1];
    __shared__ float Bs[BK][BN + 1];
    const int z = blockIdx.z;
    A += (long)z * sA; Bm += (long)z * sB; C += (long)z * sC;
    const int bm = blockIdx.y * BM, bn = blockIdx.x * BN;
    const int tid = threadIdx.x;
    constexpr int TC = BN / TN;
    const int tc = tid % TC, tr = tid / TC;
    float acc[TM][TN] = {};
    for (int k0 = 0; k0 < K; k0 += BK) {
        for (int i = tid; i < BM * 4; i += 256) {
            int m = i >> 2, k4 = (i & 3) << 2;
            float4 v = *(const float4*)(A + (long)(bm + m) * K + k0 + k4);
            As[k4][m] = v.x; As[k4 + 1][m] = v.y; As[k4 + 2][m] = v.z; As[k4 + 3][m] = v.w;
        }
        for (int i = tid; i < BK * (BN / 4); i += 256) {
            int k = i / (BN / 4), n4 = (i % (BN / 4)) * 4;
            float4 v = *(const float4*)(Bm + (long)(k0 + k) * N + bn + n4);
            Bs[k][n4] = v.x; Bs[k][n4 + 1] = v.y; Bs[k][n4 + 2] = v.z; Bs[k][n4 + 3] = v.w;
        }
        __syncthreads();
#pragma unroll
        for (int kk = 0; kk < BK; ++kk) {
            float a[TM], b[TN];
#pragma unroll
            for (int i = 0; i < TM; i++) a[i] = As[kk][tr * TM + i];
#pragma unroll
            for (int j = 0; j < TN; j++) b[j] = Bs[kk][tc * TN + j];
#pragma unroll
            for (int i = 0; i < TM; i++)
#pragma unroll
                for (int j = 0; j < TN; j++) acc[i][j] += a[i] * b[j];
        }
        __syncthreads();
    }
#pragma unroll
    for (int i = 0; i < TM; i++) {
        int m = bm + tr * TM + i;
#pragma unroll
        for (int j = 0; j < TN; j++) {
            int n = bn + tc * TN + j;
            stout(&C[(long)m * N + n], acc[i][j]);
        }
    }
}

// ---------------------------------------------------------------------------
// Masked softmax over S=256, in place.
// ---------------------------------------------------------------------------
__global__ __launch_bounds__(256) void softmax_mask(
    float* __restrict__ attn, const int* __restrict__ src_len)
{
    __shared__ float red[4];
    const int b = blockIdx.y, t = blockIdx.x, s = threadIdx.x;
    float* row = attn + ((long)b * TT + t) * SS;
    const int L = src_len[b];
    float v = (s < L) ? row[s] : -INFINITY;
    float m = v;
#pragma unroll
    for (int o = 32; o >= 1; o >>= 1) m = fmaxf(m, __shfl_xor(m, o));
    if ((s & 63) == 0) red[s >> 6] = m;
    __syncthreads();
    m = fmaxf(fmaxf(red[0], red[1]), fmaxf(red[2], red[3]));
    __syncthreads();
    float e = (s < L) ? expf(v - m) : 0.0f;
    float sum = e;
#pragma unroll
    for (int o = 32; o >= 1; o >>= 1) sum += __shfl_xor(sum, o);
    if ((s & 63) == 0) red[s >> 6] = sum;
    __syncthreads();
    sum = red[0] + red[1] + red[2] + red[3];
    row[s] = e / sum;
}

// ---------------------------------------------------------------------------
extern "C" void kernel_launch(void* const* d_in, const int* in_sizes, int n_in,
                              void* d_out, int out_size, void* d_ws, size_t ws_size,
                              hipStream_t stream)
{
    const float* trg_emb = (const float*)d_in[0];
    const float* h0      = (const float*)d_in[1];
    const float* c0      = (const float*)d_in[2];
    const float* ctx     = (const float*)d_in[3];
    const int*   src_len = (const int*)d_in[4];
    const float* W_ih    = (const float*)d_in[5];
    const float* W_hh    = (const float*)d_in[6];
    const float* b_ih    = (const float*)d_in[7];
    const float* b_hh    = (const float*)d_in[8];
    const float* W_in    = (const float*)d_in[9];
    const float* W_out   = (const float*)d_in[10];

    float* out = (float*)d_out;
    float* h_tilde = out;                          // [B,T,H]
    float* hT = out + (size_t)BB * TT * HHH;       // [1,B,H]
    float* cT = hT + (size_t)BB * HHH;             // [1,B,H]

    char* w = (char*)d_ws;
    auto take = [&](size_t bytes) { void* p = w; w += (bytes + 255) & ~(size_t)255; return p; };
    u16* trg16  = (u16*)take(8388608ull * 2);
    u16* Wih16  = (u16*)take(4194304ull * 2);
    u16* Win16  = (u16*)take(1048576ull * 2);
    u16* Wout16 = (u16*)take(2097152ull * 2);
    u16* lstm16 = (u16*)take(8388608ull * 2);
    u16* Whi    = (u16*)take(4194304ull * 2);
    u16* Wlo    = (u16*)take(4194304ull * 2);
    u32* hE     = (u32*)take(65536ull * 4);        // packed h ping-pong
    u32* hO     = (u32*)take(65536ull * 4);
    int* bar    = (int*)take(256);
    char* regionB = w;
    float* xgt = (float*)take(33554432ull * 4);    // [t][4H r=j*4+g][B] fp32
    float* q        = (float*)regionB;
    float* attn     = (float*)(regionB + 33554432ull);
    u16*   ctxout16 = (u16*)(regionB + 41943040ull);

    // barrier counter must start at 0 every call
    hipMemsetAsync(bar, 0, 256, stream);

    // prep (independent, parallel)
    f32_to_bf16<<<4096, 256, 0, stream>>>(trg_emb, trg16, 8388608);
    f32_to_bf16<<<2048, 256, 0, stream>>>(W_ih, Wih16, 4194304);
    f32_to_bf16<<<512, 256, 0, stream>>>(W_in, Win16, 1048576);
    f32_to_bf16<<<1024, 256, 0, stream>>>(W_out, Wout16, 2097152);
    split_whh<<<4096, 256, 0, stream>>>(W_hh, Whi, Wlo);
    h0_pack<<<256, 256, 0, stream>>>(h0, hE);

    // x_gates = trg_emb @ W_ih^T + (b_ih+b_hh) -> fp32 xgt[t][j*4+g][b]
    gemm_mfma_bt<false, true, float><<<dim3(32, 64), 256, 0, stream>>>(
        trg16, trg16, Wih16, xgt, 8192, 4096, 1024, 1024, b_ih, b_hh);

    // persistent LSTM scan (single launch; writes lstm16, hT, cT)
    lstm_scan4<<<SCANBLK, 512, 0, stream>>>(xgt, Whi, Wlo, c0, hE, hO,
                                            hT, cT, lstm16, bar);

    // q = lstm_out @ W_in^T (bf16 MFMA, fp32 out)
    gemm_mfma_bt<false, false, float><<<dim3(8, 64), 256, 0, stream>>>(
        lstm16, lstm16, Win16, q, 8192, 1024, 1024, 1024, nullptr, nullptr);

    // scores[b] = q[b] @ ctx[b]^T (fp32)
    gemm_bt<64, 64, 4, 4><<<dim3(4, 2, 64), 256, 0, stream>>>(
        q, ctx, attn, TT, SS, HHH,
        (long)TT * HHH, (long)SS * HHH, (long)TT * SS);

    softmax_mask<<<dim3(TT, BB, 1), 256, 0, stream>>>(attn, src_len);

    // context[b] = attn[b] @ ctx[b] (fp32 compute, bf16 out)
    gemm_bn<64, 64, 4, 4, u16><<<dim3(16, 2, 64), 256, 0, stream>>>(
        attn, ctx, ctxout16, TT, HHH, SS,
        (long)TT * SS, (long)SS * HHH, (long)TT * HHH);

    // h_tilde = tanh([context, lstm_out] @ W_out^T)
    gemm_mfma_bt<true, false, float><<<dim3(8, 64), 256, 0, stream>>>(
        ctxout16, lstm16, Wout16, h_tilde, 8192, 1024, 2048, 1024, nullptr, nullptr);
}

// Round 9
// 2796.902 us; speedup vs baseline: 2.2985x; 2.2985x over previous
//
#include <hip/hip_runtime.h>
#include <math.h>

#define BB 64
#define TT 128
#define SS 256
#define HHH 1024
#define SCANBLK 64

typedef unsigned short u16;
typedef unsigned int u32;
typedef unsigned long long u64t;
typedef __bf16 bf16x8 __attribute__((ext_vector_type(8)));
typedef float f32x4 __attribute__((ext_vector_type(4)));
typedef u16 u16x8 __attribute__((ext_vector_type(8)));

__device__ __forceinline__ float sigmoidf_(float x) { return 1.0f / (1.0f + expf(-x)); }
__device__ __forceinline__ u16 f2bf(float f) {
    __bf16 h = (__bf16)f;
    return __builtin_bit_cast(u16, h);
}
__device__ __forceinline__ float b2f(u16 u) {
    return __builtin_bit_cast(float, (u32)u << 16);
}
template <typename OT>
__device__ __forceinline__ void stout(OT* p, float v) {
    if constexpr (sizeof(OT) == 2) *p = f2bf(v); else *p = v;
}
__device__ __forceinline__ void astore(u64t* p, u64t v) {
    __hip_atomic_store(p, v, __ATOMIC_RELAXED, __HIP_MEMORY_SCOPE_AGENT);
}
__device__ __forceinline__ int afetchadd(int* p) {
    return __hip_atomic_fetch_add(p, 1, __ATOMIC_RELAXED, __HIP_MEMORY_SCOPE_AGENT);
}
__device__ __forceinline__ int aload32(const int* p) {
    return __hip_atomic_load(p, __ATOMIC_RELAXED, __HIP_MEMORY_SCOPE_AGENT);
}
__device__ __forceinline__ void astore32(int* p, int v) {
    __hip_atomic_store(p, v, __ATOMIC_RELAXED, __HIP_MEMORY_SCOPE_AGENT);
}

// ---------------------------------------------------------------------------
// fp32 → bf16 elementwise
// ---------------------------------------------------------------------------
__global__ __launch_bounds__(256) void f32_to_bf16(const float* __restrict__ in,
                                                   u16* __restrict__ out, long n) {
    long i = ((long)blockIdx.x * 256 + threadIdx.x) * 8;
    float4 a = *(const float4*)(in + i);
    float4 b = *(const float4*)(in + i + 4);
    u16x8 o;
    o[0] = f2bf(a.x); o[1] = f2bf(a.y); o[2] = f2bf(a.z); o[3] = f2bf(a.w);
    o[4] = f2bf(b.x); o[5] = f2bf(b.y); o[6] = f2bf(b.z); o[7] = f2bf(b.w);
    *(u16x8*)(out + i) = o;
}

// ---------------------------------------------------------------------------
// W_hh [row=g*1024+j][1024] fp32 -> Whi/Wlo bf16 [row'=j*4+g][1024]
// ---------------------------------------------------------------------------
__global__ __launch_bounds__(256) void split_whh(const float* __restrict__ W,
                                                 u16* __restrict__ hi,
                                                 u16* __restrict__ lo) {
    const int row = blockIdx.x;
    const int g = row >> 10, j = row & 1023;
    const int dst = (j << 2) | g;
    const int k4 = threadIdx.x << 2;
    float4 v = *(const float4*)(W + (size_t)row * 1024 + k4);
    u16 h0 = f2bf(v.x), h1 = f2bf(v.y), h2 = f2bf(v.z), h3 = f2bf(v.w);
    ushort4 hv = {h0, h1, h2, h3};
    ushort4 lv = {f2bf(v.x - b2f(h0)), f2bf(v.y - b2f(h1)),
                  f2bf(v.z - b2f(h2)), f2bf(v.w - b2f(h3))};
    *(ushort4*)(hi + (size_t)dst * 1024 + k4) = hv;
    *(ushort4*)(lo + (size_t)dst * 1024 + k4) = lv;
}

// ---------------------------------------------------------------------------
// h0 [64 b][1024 j] fp32 -> packed (hi | lo<<16) u32, same [b][j] layout
// ---------------------------------------------------------------------------
__global__ __launch_bounds__(256) void h0_pack(const float* __restrict__ h0,
                                               u32* __restrict__ out) {
    int i = blockIdx.x * 256 + threadIdx.x;
    float v = h0[i];
    u16 hi = f2bf(v);
    u16 lo = f2bf(v - b2f(hi));
    out[i] = (u32)hi | ((u32)lo << 16);
}

// ---------------------------------------------------------------------------
// MFMA bf16 GEMM (A@B^T). XGT mode writes fp32 xgt[t][j*4+g][b] + bias.
// ---------------------------------------------------------------------------
template <bool TANH, bool XGT, typename OT>
__global__ __launch_bounds__(256) void gemm_mfma_bt(
    const u16* __restrict__ A0, const u16* __restrict__ A1,
    const u16* __restrict__ B, OT* __restrict__ C,
    int M, int N, int K, int KA0,
    const float* __restrict__ bias0, const float* __restrict__ bias1)
{
    __shared__ uint4 As4[512];
    __shared__ uint4 Bs4[512];
    u16* As = (u16*)As4;
    u16* Bs = (u16*)Bs4;
    const int tid = threadIdx.x;
    const int l = tid & 63;
    const int w = tid >> 6;
    const int wm = w >> 1, wn = w & 1;
    const int tc = l & 15, tr8 = (l >> 4) << 3;
    const int m0 = blockIdx.y << 7, n0 = blockIdx.x << 7;
    f32x4 acc[4][4] = {};

    for (int k0 = 0; k0 < K; k0 += 32) {
        const u16* Ap = (k0 < KA0) ? A0 : A1;
        const int koff = (k0 < KA0) ? k0 : k0 - KA0;
#pragma unroll
        for (int r = 0; r < 2; ++r) {
            int u = tid + (r << 8);
            int row = u >> 2, q = u & 3;
            size_t arow;
            if (XGT) {
                int rr = m0 + row;
                arow = (size_t)((rr & 63) * 128 + (rr >> 6));
            } else {
                arow = (size_t)(m0 + row);
            }
            As4[u] = *(const uint4*)(Ap + arow * KA0 + koff + (q << 3));
            Bs4[u] = *(const uint4*)(B + (size_t)(n0 + row) * K + k0 + (q << 3));
        }
        __syncthreads();
        bf16x8 bfr[4];
#pragma unroll
        for (int j = 0; j < 4; ++j)
            bfr[j] = *(const bf16x8*)(Bs + ((wn << 6) + (j << 4) + tc) * 32 + tr8);
#pragma unroll
        for (int i = 0; i < 4; ++i) {
            bf16x8 af = *(const bf16x8*)(As + ((wm << 6) + (i << 4) + tc) * 32 + tr8);
#pragma unroll
            for (int j = 0; j < 4; ++j)
                acc[i][j] = __builtin_amdgcn_mfma_f32_16x16x32_bf16(af, bfr[j], acc[i][j], 0, 0, 0);
        }
        __syncthreads();
    }
#pragma unroll
    for (int j = 0; j < 4; ++j) {
        const int col = n0 + (wn << 6) + (j << 4) + tc;
        const float bias = XGT ? (bias0[col] + bias1[col]) : 0.0f;
#pragma unroll
        for (int i = 0; i < 4; ++i) {
#pragma unroll
            for (int v = 0; v < 4; ++v) {
                int r = m0 + (wm << 6) + (i << 4) + ((l >> 4) << 2) + v;
                float val = acc[i][j][v];
                if (XGT) {
                    int newr = ((col & 1023) << 2) | (col >> 10);   // j*4+g
                    ((float*)C)[(size_t)(r >> 6) * 262144 + (size_t)newr * 64 + (r & 63)] = val + bias;
                } else {
                    if (TANH) val = tanhf(val);
                    stout(&C[(size_t)r * N + col], val);
                }
            }
        }
    }
}

// ---------------------------------------------------------------------------
// Persistent LSTM scan v5. 64 blocks x 512 thr (8 waves = 2/SIMD), 128 steps.
// Block owns 16 j x 4 gates = 64 rows; waves = 4 k-quarters x 2 row-halves.
// h ring: 128 fresh slots (one per step) of packed (hi|lo) u32 [b][j].
//   Loads: NORMAL cached uint4 (L2-served; staleness impossible in-replay
//   because each slot is written once before its only read; across replays
//   any cached value is identical by determinism).
//   Stores: agent-scope relaxed atomics (memory-side, proven visible r6-r8).
// Barrier: hierarchical (8 leaf counters -> root -> generation word),
//   monotonic relaxed atomics; __syncthreads drains vmem before arrival.
// Split-precision gates = Whi@hhi + Whi@hlo + Wlo@hhi. c in registers.
// ---------------------------------------------------------------------------
__global__ __launch_bounds__(512) void lstm_scan5(
    const float* __restrict__ xgt,
    const u16* __restrict__ Whi, const u16* __restrict__ Wlo,
    const float* __restrict__ c0,
    const u32* __restrict__ h0s, u32* __restrict__ ring,
    float* __restrict__ hT, float* __restrict__ cT,
    u16* __restrict__ lstm16, int* __restrict__ bar)
{
    __shared__ float red[4][64][68];      // [kq][row][b] 69.6 KB
    __shared__ u32 tile[64][17];          // packed h-out (16 j + pad)
    const int tid = threadIdx.x;
    const int bid = blockIdx.x;
    const int kg = tid >> 6, l = tid & 63;
    const int kq = kg & 3, rh = kg >> 2;
    const int tc = l & 15, tr8 = (l >> 4) << 3;
    const int j0 = bid << 4;
    const int r0 = (bid << 6) + (rh << 5);   // this wave's 32-row base
    const int kbase = kq << 8;

    const int eb = tid & 63;
    const int ej = tid >> 6;                 // 0..7 (handles ej and ej+8)

    float cv[2];
    cv[0] = c0[(size_t)eb * 1024 + j0 + ej];
    cv[1] = c0[(size_t)eb * 1024 + j0 + ej + 8];

    for (int t = 0; t < 128; ++t) {
        const u32* hin = (t == 0) ? h0s : (ring + (size_t)(t - 1) * 65536);
        u32* hout = ring + (size_t)t * 65536;

        // xg gate values (independent of h; in flight through the MFMAs)
        float xgv[2][4];
#pragma unroll
        for (int p = 0; p < 2; ++p)
#pragma unroll
            for (int g = 0; g < 4; ++g)
                xgv[p][g] = xgt[(size_t)t * 262144 +
                                (size_t)((j0 + ej + p * 8) * 4 + g) * 64 + eb];

        f32x4 acc[2][4] = {};   // [rt][bt]
#pragma unroll
        for (int w = 0; w < 8; ++w) {
            const int k = kbase + (w << 5) + tr8;
            bf16x8 ah[2], al[2];
#pragma unroll
            for (int rt = 0; rt < 2; ++rt) {
                ah[rt] = *(const bf16x8*)(Whi + (size_t)(r0 + rt * 16 + tc) * 1024 + k);
                al[rt] = *(const bf16x8*)(Wlo + (size_t)(r0 + rt * 16 + tc) * 1024 + k);
            }
            bf16x8 bh[4], bl[4];
#pragma unroll
            for (int bt = 0; bt < 4; ++bt) {
                const u32* src = hin + (size_t)(bt * 16 + tc) * 1024 + k;
                uint4 d0 = *(const uint4*)src;
                uint4 d1 = *(const uint4*)(src + 4);
                union { u32 u[4]; bf16x8 v; } H, L;
                H.u[0] = __builtin_amdgcn_perm(d0.y, d0.x, 0x05040100u);
                L.u[0] = __builtin_amdgcn_perm(d0.y, d0.x, 0x07060302u);
                H.u[1] = __builtin_amdgcn_perm(d0.w, d0.z, 0x05040100u);
                L.u[1] = __builtin_amdgcn_perm(d0.w, d0.z, 0x07060302u);
                H.u[2] = __builtin_amdgcn_perm(d1.y, d1.x, 0x05040100u);
                L.u[2] = __builtin_amdgcn_perm(d1.y, d1.x, 0x07060302u);
                H.u[3] = __builtin_amdgcn_perm(d1.w, d1.z, 0x05040100u);
                L.u[3] = __builtin_amdgcn_perm(d1.w, d1.z, 0x07060302u);
                bh[bt] = H.v;
                bl[bt] = L.v;
            }
#pragma unroll
            for (int rt = 0; rt < 2; ++rt)
#pragma unroll
                for (int bt = 0; bt < 4; ++bt) {
                    acc[rt][bt] = __builtin_amdgcn_mfma_f32_16x16x32_bf16(ah[rt], bh[bt], acc[rt][bt], 0, 0, 0);
                    acc[rt][bt] = __builtin_amdgcn_mfma_f32_16x16x32_bf16(ah[rt], bl[bt], acc[rt][bt], 0, 0, 0);
                    acc[rt][bt] = __builtin_amdgcn_mfma_f32_16x16x32_bf16(al[rt], bh[bt], acc[rt][bt], 0, 0, 0);
                }
        }
#pragma unroll
        for (int rt = 0; rt < 2; ++rt)
#pragma unroll
            for (int bt = 0; bt < 4; ++bt)
#pragma unroll
                for (int v = 0; v < 4; ++v)
                    red[kq][(rh << 5) + (rt << 4) + ((l >> 4) << 2) + v][(bt << 4) + tc] = acc[rt][bt][v];
        __syncthreads();

        // epilogue: thread -> (b=eb, jl=ej and ej+8)
#pragma unroll
        for (int p = 0; p < 2; ++p) {
            const int jl = ej + p * 8;
            float gate[4];
#pragma unroll
            for (int g = 0; g < 4; ++g) {
                int rr = (jl << 2) + g;
                gate[g] = red[0][rr][eb] + red[1][rr][eb] +
                          red[2][rr][eb] + red[3][rr][eb] + xgv[p][g];
            }
            float ii = sigmoidf_(gate[0]);
            float ff = sigmoidf_(gate[1]);
            float gg = tanhf(gate[2]);
            float oo = sigmoidf_(gate[3]);
            float cn = ff * cv[p] + ii * gg;
            float hn = oo * tanhf(cn);
            cv[p] = cn;
            u16 hh = f2bf(hn);
            u16 hl = f2bf(hn - b2f(hh));
            tile[eb][jl] = (u32)hh | ((u32)hl << 16);
            if (t == 127) {
                hT[(size_t)eb * 1024 + j0 + jl] = hn;
                cT[(size_t)eb * 1024 + j0 + jl] = cn;
            }
        }
        __syncthreads();

        // store phase: h ring slot (atomic 8B, coalesced) + lstm_out (normal)
        {
            const int b = tid >> 3, jp = tid & 7;
            u32 w0 = tile[b][jp * 2], w1 = tile[b][jp * 2 + 1];
            u64t v = (u64t)w0 | ((u64t)w1 << 32);
            astore((u64t*)hout + ((((size_t)b << 10) + j0) >> 1) + jp, v);
            u32 hi2 = __builtin_amdgcn_perm(w1, w0, 0x05040100u);
            *(u32*)(lstm16 + ((size_t)b * 128 + t) * 1024 + j0 + jp * 2) = hi2;
        }

        // hierarchical grid barrier (monotonic; leaves -> root -> generation)
        if (t < 127) {
            __syncthreads();    // drains vmem: h stores are memory-side-visible
            if (tid == 0) {
                int a = afetchadd(&bar[(bid & 7) * 32]);
                if ((a & 7) == 7) {
                    int r = afetchadd(&bar[256]);
                    if ((r & 7) == 7) astore32(&bar[288], t + 1);
                }
                while (aload32(&bar[288]) < t + 1) __builtin_amdgcn_s_sleep(4);
            }
            __syncthreads();
        }
    }
}

// ---------------------------------------------------------------------------
// fp32 GEMM C = A @ B^T (scores), batched via blockIdx.z.
// ---------------------------------------------------------------------------
template <int BM, int BN, int TM, int TN>
__global__ __launch_bounds__(256) void gemm_bt(
    const float* __restrict__ A, const float* __restrict__ Bm, float* __restrict__ C,
    int M, int N, int K, long sA, long sB, long sC)
{
    constexpr int BK = 16;
    __shared__ float As[BK][BM + 1];
    __shared__ float Bs[BK][BN + 1];
    const int z = blockIdx.z;
    A += (long)z * sA; Bm += (long)z * sB; C += (long)z * sC;
    const int bm = blockIdx.y * BM, bn = blockIdx.x * BN;
    const int tid = threadIdx.x;
    constexpr int TC = BN / TN;
    const int tc = tid % TC, tr = tid / TC;
    float acc[TM][TN] = {};
    for (int k0 = 0; k0 < K; k0 += BK) {
        for (int i = tid; i < BM * 4; i += 256) {
            int m = i >> 2, k4 = (i & 3) << 2;
            float4 v = *(const float4*)(A + (long)(bm + m) * K + k0 + k4);
            As[k4][m] = v.x; As[k4 + 1][m] = v.y; As[k4 + 2][m] = v.z; As[k4 + 3][m] = v.w;
        }
        for (int i = tid; i < BN * 4; i += 256) {
            int n = i >> 2, k4 = (i & 3) << 2;
            float4 v = *(const float4*)(Bm + (long)(bn + n) * K + k0 + k4);
            Bs[k4][n] = v.x; Bs[k4 + 1][n] = v.y; Bs[k4 + 2][n] = v.z; Bs[k4 + 3][n] = v.w;
        }
        __syncthreads();
#pragma unroll
        for (int kk = 0; kk < BK; ++kk) {
            float a[TM], b[TN];
#pragma unroll
            for (int i = 0; i < TM; i++) a[i] = As[kk][tr * TM + i];
#pragma unroll
            for (int j = 0; j < TN; j++) b[j] = Bs[kk][tc * TN + j];
#pragma unroll
            for (int i = 0; i < TM; i++)
#pragma unroll
                for (int j = 0; j < TN; j++) acc[i][j] += a[i] * b[j];
        }
        __syncthreads();
    }
#pragma unroll
    for (int i = 0; i < TM; i++) {
        int m = bm + tr * TM + i;
#pragma unroll
        for (int j = 0; j < TN; j++) {
            int n = bn + tc * TN + j;
            C[(long)m * N + n] = acc[i][j];
        }
    }
}

// ---------------------------------------------------------------------------
// fp32 GEMM C = A @ B (context = attn @ ctx), OT output.
// ---------------------------------------------------------------------------
template <int BM, int BN, int TM, int TN, typename OT>
__global__ __launch_bounds__(256) void gemm_bn(
    const float* __restrict__ A, const float* __restrict__ Bm, OT* __restrict__ C,
    int M, int N, int K, long sA, long sB, long sC)
{
    constexpr int BK = 16;
    __shared__ float As[BK][BM + 1];
    __shared__ float Bs[BK][BN + 1];
    const int z = blockIdx.z;
    A += (long)z * sA; Bm += (long)z * sB; C += (long)z * sC;
    const int bm = blockIdx.y * BM, bn = blockIdx.x * BN;
    const int tid = threadIdx.x;
    constexpr int TC = BN / TN;
    const int tc = tid % TC, tr = tid / TC;
    float acc[TM][TN] = {};
    for (int k0 = 0; k0 < K; k0 += BK) {
        for (int i = tid; i < BM * 4; i += 256) {
            int m = i >> 2, k4 = (i & 3) << 2;
            float4 v = *(const float4*)(A + (long)(bm + m) * K + k0 + k4);
            As[k4][m] = v.x; As[k4 + 1][m] = v.y; As[k4 + 2][m] = v.z; As[k4 + 3][m] = v.w;
        }
        for (int i = tid; i < BK * (BN / 4); i += 256) {
            int k = i / (BN / 4), n4 = (i % (BN / 4)) * 4;
            float4 v = *(const float4*)(Bm + (long)(k0 + k) * N + bn + n4);
            Bs[k][n4] = v.x; Bs[k][n4 + 1] = v.y; Bs[k][n4 + 2] = v.z; Bs[k][n4 + 3] = v.w;
        }
        __syncthreads();
#pragma unroll
        for (int kk = 0; kk < BK; ++kk) {
            float a[TM], b[TN];
#pragma unroll
            for (int i = 0; i < TM; i++) a[i] = As[kk][tr * TM + i];
#pragma unroll
            for (int j = 0; j < TN; j++) b[j] = Bs[kk][tc * TN + j];
#pragma unroll
            for (int i = 0; i < TM; i++)
#pragma unroll
                for (int j = 0; j < TN; j++) acc[i][j] += a[i] * b[j];
        }
        __syncthreads();
    }
#pragma unroll
    for (int i = 0; i < TM; i++) {
        int m = bm + tr * TM + i;
#pragma unroll
        for (int j = 0; j < TN; j++) {
            int n = bn + tc * TN + j;
            stout(&C[(long)m * N + n], acc[i][j]);
        }
    }
}

// ---------------------------------------------------------------------------
// Masked softmax over S=256, in place.
// ---------------------------------------------------------------------------
__global__ __launch_bounds__(256) void softmax_mask(
    float* __restrict__ attn, const int* __restrict__ src_len)
{
    __shared__ float red[4];
    const int b = blockIdx.y, t = blockIdx.x, s = threadIdx.x;
    float* row = attn + ((long)b * TT + t) * SS;
    const int L = src_len[b];
    float v = (s < L) ? row[s] : -INFINITY;
    float m = v;
#pragma unroll
    for (int o = 32; o >= 1; o >>= 1) m = fmaxf(m, __shfl_xor(m, o));
    if ((s & 63) == 0) red[s >> 6] = m;
    __syncthreads();
    m = fmaxf(fmaxf(red[0], red[1]), fmaxf(red[2], red[3]));
    __syncthreads();
    float e = (s < L) ? expf(v - m) : 0.0f;
    float sum = e;
#pragma unroll
    for (int o = 32; o >= 1; o >>= 1) sum += __shfl_xor(sum, o);
    if ((s & 63) == 0) red[s >> 6] = sum;
    __syncthreads();
    sum = red[0] + red[1] + red[2] + red[3];
    row[s] = e / sum;
}

// ---------------------------------------------------------------------------
extern "C" void kernel_launch(void* const* d_in, const int* in_sizes, int n_in,
                              void* d_out, int out_size, void* d_ws, size_t ws_size,
                              hipStream_t stream)
{
    const float* trg_emb = (const float*)d_in[0];
    const float* h0      = (const float*)d_in[1];
    const float* c0      = (const float*)d_in[2];
    const float* ctx     = (const float*)d_in[3];
    const int*   src_len = (const int*)d_in[4];
    const float* W_ih    = (const float*)d_in[5];
    const float* W_hh    = (const float*)d_in[6];
    const float* b_ih    = (const float*)d_in[7];
    const float* b_hh    = (const float*)d_in[8];
    const float* W_in    = (const float*)d_in[9];
    const float* W_out   = (const float*)d_in[10];

    float* out = (float*)d_out;
    float* h_tilde = out;                          // [B,T,H]
    float* hT = out + (size_t)BB * TT * HHH;       // [1,B,H]
    float* cT = hT + (size_t)BB * HHH;             // [1,B,H]

    char* w = (char*)d_ws;
    auto take = [&](size_t bytes) { void* p = w; w += (bytes + 255) & ~(size_t)255; return p; };
    // ring (128 slots x 256 KB = 32 MB) aliases trg16+Wih16+spare: the ring is
    // written only inside lstm_scan5, which runs after the xgt GEMM consumed
    // trg16/Wih16 (stream-ordered), so the overlap is safe.
    char* base0 = w;
    u16* trg16  = (u16*)take(8388608ull * 2);      // 16.78 MB
    u16* Wih16  = (u16*)take(4194304ull * 2);      //  8.39 MB
    take(8388608ull);                              //  8.39 MB ring tail spare
    u32* ring   = (u32*)base0;                     // 33.55 MB total
    u32* h0s    = (u32*)take(262144ull);           // h slot for t=0
    u16* Win16  = (u16*)take(1048576ull * 2);
    u16* Wout16 = (u16*)take(2097152ull * 2);
    u16* lstm16 = (u16*)take(8388608ull * 2);
    u16* Whi    = (u16*)take(4194304ull * 2);
    u16* Wlo    = (u16*)take(4194304ull * 2);
    int* bar    = (int*)take(4096);
    char* regionB = w;
    float* xgt = (float*)take(33554432ull * 4);    // [t][4H r=j*4+g][B] fp32
    float* q        = (float*)regionB;
    float* attn     = (float*)(regionB + 33554432ull);
    u16*   ctxout16 = (u16*)(regionB + 41943040ull);

    // barrier counters must start at 0 every call
    hipMemsetAsync(bar, 0, 4096, stream);

    // prep (independent, parallel)
    f32_to_bf16<<<4096, 256, 0, stream>>>(trg_emb, trg16, 8388608);
    f32_to_bf16<<<2048, 256, 0, stream>>>(W_ih, Wih16, 4194304);
    f32_to_bf16<<<512, 256, 0, stream>>>(W_in, Win16, 1048576);
    f32_to_bf16<<<1024, 256, 0, stream>>>(W_out, Wout16, 2097152);
    split_whh<<<4096, 256, 0, stream>>>(W_hh, Whi, Wlo);
    h0_pack<<<256, 256, 0, stream>>>(h0, h0s);

    // x_gates = trg_emb @ W_ih^T + (b_ih+b_hh) -> fp32 xgt[t][j*4+g][b]
    gemm_mfma_bt<false, true, float><<<dim3(32, 64), 256, 0, stream>>>(
        trg16, trg16, Wih16, xgt, 8192, 4096, 1024, 1024, b_ih, b_hh);

    // persistent LSTM scan (single launch; writes lstm16, hT, cT)
    lstm_scan5<<<SCANBLK, 512, 0, stream>>>(xgt, Whi, Wlo, c0, h0s, ring,
                                            hT, cT, lstm16, bar);

    // q = lstm_out @ W_in^T (bf16 MFMA, fp32 out)
    gemm_mfma_bt<false, false, float><<<dim3(8, 64), 256, 0, stream>>>(
        lstm16, lstm16, Win16, q, 8192, 1024, 1024, 1024, nullptr, nullptr);

    // scores[b] = q[b] @ ctx[b]^T (fp32)
    gemm_bt<64, 64, 4, 4><<<dim3(4, 2, 64), 256, 0, stream>>>(
        q, ctx, attn, TT, SS, HHH,
        (long)TT * HHH, (long)SS * HHH, (long)TT * SS);

    softmax_mask<<<dim3(TT, BB, 1), 256, 0, stream>>>(attn, src_len);

    // context[b] = attn[b] @ ctx[b] (fp32 compute, bf16 out)
    gemm_bn<64, 64, 4, 4, u16><<<dim3(16, 2, 64), 256, 0, stream>>>(
        attn, ctx, ctxout16, TT, HHH, SS,
        (long)TT * SS, (long)SS * HHH, (long)TT * HHH);

    // h_tilde = tanh([context, lstm_out] @ W_out^T)
    gemm_mfma_bt<true, false, float><<<dim3(8, 64), 256, 0, stream>>>(
        ctxout16, lstm16, Wout16, h_tilde, 8192, 1024, 2048, 1024, nullptr, nullptr);
}

// Round 10
// 1953.057 us; speedup vs baseline: 3.2916x; 1.4321x over previous
//
#include <hip/hip_runtime.h>
#include <math.h>

#define BB 64
#define TT 128
#define SS 256
#define HHH 1024
#define SCANBLK 128

typedef unsigned short u16;
typedef unsigned int u32;
typedef unsigned long long u64t;
typedef __bf16 bf16x8 __attribute__((ext_vector_type(8)));
typedef float f32x4 __attribute__((ext_vector_type(4)));
typedef u16 u16x8 __attribute__((ext_vector_type(8)));

__device__ __forceinline__ float sigmoidf_(float x) { return 1.0f / (1.0f + expf(-x)); }
__device__ __forceinline__ u16 f2bf(float f) {
    __bf16 h = (__bf16)f;
    return __builtin_bit_cast(u16, h);
}
__device__ __forceinline__ float b2f(u16 u) {
    return __builtin_bit_cast(float, (u32)u << 16);
}
template <typename OT>
__device__ __forceinline__ void stout(OT* p, float v) {
    if constexpr (sizeof(OT) == 2) *p = f2bf(v); else *p = v;
}
__device__ __forceinline__ void astore(u64t* p, u64t v) {
    __hip_atomic_store(p, v, __ATOMIC_RELAXED, __HIP_MEMORY_SCOPE_AGENT);
}
__device__ __forceinline__ int afetchadd(int* p) {
    return __hip_atomic_fetch_add(p, 1, __ATOMIC_RELAXED, __HIP_MEMORY_SCOPE_AGENT);
}
__device__ __forceinline__ int aload32(const int* p) {
    return __hip_atomic_load(p, __ATOMIC_RELAXED, __HIP_MEMORY_SCOPE_AGENT);
}
__device__ __forceinline__ void astore32(int* p, int v) {
    __hip_atomic_store(p, v, __ATOMIC_RELAXED, __HIP_MEMORY_SCOPE_AGENT);
}

// ---------------------------------------------------------------------------
// fp32 → bf16 elementwise
// ---------------------------------------------------------------------------
__global__ __launch_bounds__(256) void f32_to_bf16(const float* __restrict__ in,
                                                   u16* __restrict__ out, long n) {
    long i = ((long)blockIdx.x * 256 + threadIdx.x) * 8;
    float4 a = *(const float4*)(in + i);
    float4 b = *(const float4*)(in + i + 4);
    u16x8 o;
    o[0] = f2bf(a.x); o[1] = f2bf(a.y); o[2] = f2bf(a.z); o[3] = f2bf(a.w);
    o[4] = f2bf(b.x); o[5] = f2bf(b.y); o[6] = f2bf(b.z); o[7] = f2bf(b.w);
    *(u16x8*)(out + i) = o;
}

// ---------------------------------------------------------------------------
// W_hh fp32 -> fragment-major split-precision WF.
// frag_id = (((bid*4+kq)*8+w)*2+rh)*2+plane ; frag = 64 lanes x 8 u16 (1KB).
// lane l holds W[row' = bid*32+rh*16+(l&15)][k = kq*256+w*32+(l>>4)*8 .. +8]
// where row' = j*4+g (gate-interleaved row order).
// ---------------------------------------------------------------------------
__global__ __launch_bounds__(128) void wfrag_build(const float* __restrict__ W,
                                                   u16* __restrict__ WF) {
    const int w = blockIdx.x, kq = blockIdx.y, bid = blockIdx.z;
    const int t = threadIdx.x;
    const int rh = t >> 6, lane = t & 63;
    const int rowp = bid * 32 + rh * 16 + (lane & 15);
    const int g = rowp & 3, jrow = rowp >> 2;
    const int k = kq * 256 + w * 32 + (lane >> 4) * 8;
    const float* src = W + ((size_t)(g * 1024 + jrow) << 10) + k;
    float4 v0 = *(const float4*)src;
    float4 v1 = *(const float4*)(src + 4);
    float vv[8] = {v0.x, v0.y, v0.z, v0.w, v1.x, v1.y, v1.z, v1.w};
    u16x8 hi, lo;
#pragma unroll
    for (int i = 0; i < 8; ++i) {
        u16 h = f2bf(vv[i]);
        hi[i] = h;
        lo[i] = f2bf(vv[i] - b2f(h));
    }
    size_t fr = ((((size_t)bid * 4 + kq) * 8 + w) * 2 + rh) * 2;
    *(u16x8*)(WF + fr * 512 + (size_t)lane * 8) = hi;
    *(u16x8*)(WF + (fr + 1) * 512 + (size_t)lane * 8) = lo;
}

// ---------------------------------------------------------------------------
// h0 fp32 [64 b][1024 j] -> fragment-major hi/lo slot (t=0 ring input).
// slot frag_id = ((kq*8+w)*4+bt)*2+plane ; lane l elem e =
//   h[b = bt*16+(l&15)][j = kq*256+w*32+(l>>4)*8 + e]
// ---------------------------------------------------------------------------
__global__ __launch_bounds__(256) void h0frag(const float* __restrict__ h0,
                                              u16* __restrict__ slot) {
    int i = blockIdx.x * 256 + threadIdx.x;   // 8192 = 64 b x 128 j-groups
    int b = i >> 7, jg = i & 127;
    int j = jg << 3;
    const float* src = h0 + ((size_t)b << 10) + j;
    float4 v0 = *(const float4*)src;
    float4 v1 = *(const float4*)(src + 4);
    float vv[8] = {v0.x, v0.y, v0.z, v0.w, v1.x, v1.y, v1.z, v1.w};
    u16x8 hi, lo;
#pragma unroll
    for (int e = 0; e < 8; ++e) {
        u16 h = f2bf(vv[e]);
        hi[e] = h;
        lo[e] = f2bf(vv[e] - b2f(h));
    }
    int kq = j >> 8, w = (j >> 5) & 7, tr = (j >> 3) & 3;
    int bt = b >> 4, lane = tr * 16 + (b & 15);
    size_t fb = (((size_t)kq * 8 + w) * 4 + bt) * 2;
    *(u16x8*)(slot + fb * 512 + (size_t)lane * 8) = hi;
    *(u16x8*)(slot + (fb + 1) * 512 + (size_t)lane * 8) = lo;
}

// ---------------------------------------------------------------------------
// MFMA bf16 GEMM (A@B^T). XGT mode writes fp32 xgt[t][j*4+g][b] + bias.
// ---------------------------------------------------------------------------
template <bool TANH, bool XGT, typename OT>
__global__ __launch_bounds__(256) void gemm_mfma_bt(
    const u16* __restrict__ A0, const u16* __restrict__ A1,
    const u16* __restrict__ B, OT* __restrict__ C,
    int M, int N, int K, int KA0,
    const float* __restrict__ bias0, const float* __restrict__ bias1)
{
    __shared__ uint4 As4[512];
    __shared__ uint4 Bs4[512];
    u16* As = (u16*)As4;
    u16* Bs = (u16*)Bs4;
    const int tid = threadIdx.x;
    const int l = tid & 63;
    const int w = tid >> 6;
    const int wm = w >> 1, wn = w & 1;
    const int tc = l & 15, tr8 = (l >> 4) << 3;
    const int m0 = blockIdx.y << 7, n0 = blockIdx.x << 7;
    f32x4 acc[4][4] = {};

    for (int k0 = 0; k0 < K; k0 += 32) {
        const u16* Ap = (k0 < KA0) ? A0 : A1;
        const int koff = (k0 < KA0) ? k0 : k0 - KA0;
#pragma unroll
        for (int r = 0; r < 2; ++r) {
            int u = tid + (r << 8);
            int row = u >> 2, q = u & 3;
            size_t arow;
            if (XGT) {
                int rr = m0 + row;
                arow = (size_t)((rr & 63) * 128 + (rr >> 6));
            } else {
                arow = (size_t)(m0 + row);
            }
            As4[u] = *(const uint4*)(Ap + arow * KA0 + koff + (q << 3));
            Bs4[u] = *(const uint4*)(B + (size_t)(n0 + row) * K + k0 + (q << 3));
        }
        __syncthreads();
        bf16x8 bfr[4];
#pragma unroll
        for (int j = 0; j < 4; ++j)
            bfr[j] = *(const bf16x8*)(Bs + ((wn << 6) + (j << 4) + tc) * 32 + tr8);
#pragma unroll
        for (int i = 0; i < 4; ++i) {
            bf16x8 af = *(const bf16x8*)(As + ((wm << 6) + (i << 4) + tc) * 32 + tr8);
#pragma unroll
            for (int j = 0; j < 4; ++j)
                acc[i][j] = __builtin_amdgcn_mfma_f32_16x16x32_bf16(af, bfr[j], acc[i][j], 0, 0, 0);
        }
        __syncthreads();
    }
#pragma unroll
    for (int j = 0; j < 4; ++j) {
        const int col = n0 + (wn << 6) + (j << 4) + tc;
        const float bias = XGT ? (bias0[col] + bias1[col]) : 0.0f;
#pragma unroll
        for (int i = 0; i < 4; ++i) {
#pragma unroll
            for (int v = 0; v < 4; ++v) {
                int r = m0 + (wm << 6) + (i << 4) + ((l >> 4) << 2) + v;
                float val = acc[i][j][v];
                if (XGT) {
                    int newr = ((col & 1023) << 2) | (col >> 10);   // j*4+g
                    ((float*)C)[(size_t)(r >> 6) * 262144 + (size_t)newr * 64 + (r & 63)] = val + bias;
                } else {
                    if (TANH) val = tanhf(val);
                    stout(&C[(size_t)r * N + col], val);
                }
            }
        }
    }
}

// ---------------------------------------------------------------------------
// Persistent LSTM scan v6. 128 blocks x 512 thr (8 waves = 2/SIMD), 128 steps.
// Block owns 8 j x 4 gates = 32 rows; waves = 4 k-quarters x 2 row-halves.
// W fragments live in REGISTERS for the whole kernel (16 frags = 64 VGPR).
// h ring: 128 fragment-major slots; reads = normal cached 16B/lane frag
// loads (fully coalesced); writes = coalesced 8B memory-side atomics.
// 2-deep register pipeline over the 8 k-windows (static A/B buffers).
// Hierarchical barrier: 16 leaves x 8 -> root -> generation word.
// Split-precision gates (Whi@hhi + Whi@hlo + Wlo@hhi), bit-identical to r9.
// ---------------------------------------------------------------------------
__global__ __launch_bounds__(512) void lstm_scan6(
    const float* __restrict__ xgt, const u16* __restrict__ WF,
    const float* __restrict__ c0,
    const u16* __restrict__ h0s, u16* __restrict__ ring,
    float* __restrict__ hT, float* __restrict__ cT,
    u16* __restrict__ lstm16, int* __restrict__ bar)
{
    __shared__ float red[4][32][68];             // 34.8 KB
    __shared__ __align__(16) u16 tileh[64][8];   // 1 KB
    __shared__ __align__(16) u16 tilel[64][8];
    const int tid = threadIdx.x;
    const int bid = blockIdx.x;
    const int kg = tid >> 6, l = tid & 63;
    const int kq = kg & 3, rh = kg >> 2;
    const int j0 = bid << 3;
    const int eb = tid & 63;
    const int ej = tid >> 6;

    // W fragments -> registers (held for all 128 steps)
    bf16x8 wf0[8], wf1[8];
#pragma unroll
    for (int w = 0; w < 8; ++w) {
        size_t fr = ((((size_t)bid * 4 + kq) * 8 + w) * 2 + rh) * 2;
        wf0[w] = *(const bf16x8*)(WF + fr * 512 + (size_t)l * 8);
        wf1[w] = *(const bf16x8*)(WF + (fr + 1) * 512 + (size_t)l * 8);
    }
    float cv = c0[(size_t)eb * 1024 + j0 + ej];

    for (int t = 0; t < 128; ++t) {
        const u16* hin = (t == 0) ? h0s : (ring + (size_t)(t - 1) * 131072);
        u16* hout = ring + (size_t)t * 131072;

        // xg gate values (independent of h; in flight through the MFMAs)
        float xgv[4];
#pragma unroll
        for (int g = 0; g < 4; ++g)
            xgv[g] = xgt[(size_t)t * 262144 + (size_t)(((j0 + ej) << 2) + g) * 64 + eb];

        f32x4 acc[4] = {};
        bf16x8 hbA[4][2], hbB[4][2];
#define LDW(HB, W)                                                             \
        {                                                                      \
            _Pragma("unroll")                                                  \
            for (int bt = 0; bt < 4; ++bt) {                                   \
                size_t fb = (((size_t)kq * 8 + (W)) * 4 + bt) * 2;             \
                HB[bt][0] = *(const bf16x8*)(hin + fb * 512 + (size_t)l * 8);  \
                HB[bt][1] = *(const bf16x8*)(hin + (fb + 1) * 512 + (size_t)l * 8); \
            }                                                                  \
        }
        LDW(hbA, 0)
#pragma unroll
        for (int w = 0; w < 8; w += 2) {
            LDW(hbB, w + 1)
#pragma unroll
            for (int bt = 0; bt < 4; ++bt) {
                acc[bt] = __builtin_amdgcn_mfma_f32_16x16x32_bf16(wf0[w], hbA[bt][0], acc[bt], 0, 0, 0);
                acc[bt] = __builtin_amdgcn_mfma_f32_16x16x32_bf16(wf0[w], hbA[bt][1], acc[bt], 0, 0, 0);
                acc[bt] = __builtin_amdgcn_mfma_f32_16x16x32_bf16(wf1[w], hbA[bt][0], acc[bt], 0, 0, 0);
            }
            if (w + 2 < 8) LDW(hbA, w + 2)
#pragma unroll
            for (int bt = 0; bt < 4; ++bt) {
                acc[bt] = __builtin_amdgcn_mfma_f32_16x16x32_bf16(wf0[w + 1], hbB[bt][0], acc[bt], 0, 0, 0);
                acc[bt] = __builtin_amdgcn_mfma_f32_16x16x32_bf16(wf0[w + 1], hbB[bt][1], acc[bt], 0, 0, 0);
                acc[bt] = __builtin_amdgcn_mfma_f32_16x16x32_bf16(wf1[w + 1], hbB[bt][0], acc[bt], 0, 0, 0);
            }
        }
#undef LDW

#pragma unroll
        for (int bt = 0; bt < 4; ++bt)
#pragma unroll
            for (int v = 0; v < 4; ++v)
                red[kq][(rh << 4) + ((l >> 4) << 2) + v][(bt << 4) + (l & 15)] = acc[bt][v];
        __syncthreads();

        // epilogue: one (b=eb, j=j0+ej) per thread
        {
            float gate[4];
#pragma unroll
            for (int g = 0; g < 4; ++g) {
                int rr = (ej << 2) + g;
                gate[g] = red[0][rr][eb] + red[1][rr][eb] +
                          red[2][rr][eb] + red[3][rr][eb] + xgv[g];
            }
            float ii = sigmoidf_(gate[0]);
            float ff = sigmoidf_(gate[1]);
            float gg = tanhf(gate[2]);
            float oo = sigmoidf_(gate[3]);
            float cn = ff * cv + ii * gg;
            float hn = oo * tanhf(cn);
            cv = cn;
            u16 hh = f2bf(hn);
            tileh[eb][ej] = hh;
            tilel[eb][ej] = f2bf(hn - b2f(hh));
            if (t == 127) {
                hT[(size_t)eb * 1024 + j0 + ej] = hn;
                cT[(size_t)eb * 1024 + j0 + ej] = cn;
            }
        }
        __syncthreads();

        // store phase: frag-layout ring slot (coalesced 8B atomics) + lstm16
        {
            const int kqb = bid >> 5, wb = (bid >> 2) & 7, trb = bid & 3;
            if (tid < 64) {
                int b = tid;
                int bt = b >> 4, lane = trb * 16 + (b & 15);
                size_t fb = (((size_t)kqb * 8 + wb) * 4 + bt) * 2;
                u64t* dst = (u64t*)(hout + fb * 512 + (size_t)lane * 8);
                const u64t* s = (const u64t*)&tileh[b][0];
                astore(dst, s[0]);
                astore(dst + 1, s[1]);
                *(uint4*)(lstm16 + ((size_t)b * 128 + t) * 1024 + j0) = *(const uint4*)&tileh[b][0];
            } else if (tid < 128) {
                int b = tid - 64;
                int bt = b >> 4, lane = trb * 16 + (b & 15);
                size_t fb = (((size_t)kqb * 8 + wb) * 4 + bt) * 2 + 1;
                u64t* dst = (u64t*)(hout + fb * 512 + (size_t)lane * 8);
                const u64t* s = (const u64t*)&tilel[b][0];
                astore(dst, s[0]);
                astore(dst + 1, s[1]);
            }
        }

        // hierarchical grid barrier (vmem drained by syncthreads first)
        if (t < 127) {
            __syncthreads();
            if (tid == 0) {
                int a = afetchadd(&bar[(bid & 15) * 16]);
                if ((a & 7) == 7) {
                    int r = afetchadd(&bar[512]);
                    if ((r & 15) == 15) astore32(&bar[520], t + 1);
                }
                while (aload32(&bar[520]) < t + 1) __builtin_amdgcn_s_sleep(1);
            }
            __syncthreads();
        }
    }
}

// ---------------------------------------------------------------------------
// fp32 GEMM C = A @ B^T (scores), batched via blockIdx.z.
// ---------------------------------------------------------------------------
template <int BM, int BN, int TM, int TN>
__global__ __launch_bounds__(256) void gemm_bt(
    const float* __restrict__ A, const float* __restrict__ Bm, float* __restrict__ C,
    int M, int N, int K, long sA, long sB, long sC)
{
    constexpr int BK = 16;
    __shared__ float As[BK][BM + 1];
    __shared__ float Bs[BK][BN + 1];
    const int z = blockIdx.z;
    A += (long)z * sA; Bm += (long)z * sB; C += (long)z * sC;
    const int bm = blockIdx.y * BM, bn = blockIdx.x * BN;
    const int tid = threadIdx.x;
    constexpr int TC = BN / TN;
    const int tc = tid % TC, tr = tid / TC;
    float acc[TM][TN] = {};
    for (int k0 = 0; k0 < K; k0 += BK) {
        for (int i = tid; i < BM * 4; i += 256) {
            int m = i >> 2, k4 = (i & 3) << 2;
            float4 v = *(const float4*)(A + (long)(bm + m) * K + k0 + k4);
            As[k4][m] = v.x; As[k4 + 1][m] = v.y; As[k4 + 2][m] = v.z; As[k4 + 3][m] = v.w;
        }
        for (int i = tid; i < BN * 4; i += 256) {
            int n = i >> 2, k4 = (i & 3) << 2;
            float4 v = *(const float4*)(Bm + (long)(bn + n) * K + k0 + k4);
            Bs[k4][n] = v.x; Bs[k4 + 1][n] = v.y; Bs[k4 + 2][n] = v.z; Bs[k4 + 3][n] = v.w;
        }
        __syncthreads();
#pragma unroll
        for (int kk = 0; kk < BK; ++kk) {
            float a[TM], b[TN];
#pragma unroll
            for (int i = 0; i < TM; i++) a[i] = As[kk][tr * TM + i];
#pragma unroll
            for (int j = 0; j < TN; j++) b[j] = Bs[kk][tc * TN + j];
#pragma unroll
            for (int i = 0; i < TM; i++)
#pragma unroll
                for (int j = 0; j < TN; j++) acc[i][j] += a[i] * b[j];
        }
        __syncthreads();
    }
#pragma unroll
    for (int i = 0; i < TM; i++) {
        int m = bm + tr * TM + i;
#pragma unroll
        for (int j = 0; j < TN; j++) {
            int n = bn + tc * TN + j;
            C[(long)m * N + n] = acc[i][j];
        }
    }
}

// ---------------------------------------------------------------------------
// fp32 GEMM C = A @ B (context = attn @ ctx), OT output.
// ---------------------------------------------------------------------------
template <int BM, int BN, int TM, int TN, typename OT>
__global__ __launch_bounds__(256) void gemm_bn(
    const float* __restrict__ A, const float* __restrict__ Bm, OT* __restrict__ C,
    int M, int N, int K, long sA, long sB, long sC)
{
    constexpr int BK = 16;
    __shared__ float As[BK][BM + 1];
    __shared__ float Bs[BK][BN + 1];
    const int z = blockIdx.z;
    A += (long)z * sA; Bm += (long)z * sB; C += (long)z * sC;
    const int bm = blockIdx.y * BM, bn = blockIdx.x * BN;
    const int tid = threadIdx.x;
    constexpr int TC = BN / TN;
    const int tc = tid % TC, tr = tid / TC;
    float acc[TM][TN] = {};
    for (int k0 = 0; k0 < K; k0 += BK) {
        for (int i = tid; i < BM * 4; i += 256) {
            int m = i >> 2, k4 = (i & 3) << 2;
            float4 v = *(const float4*)(A + (long)(bm + m) * K + k0 + k4);
            As[k4][m] = v.x; As[k4 + 1][m] = v.y; As[k4 + 2][m] = v.z; As[k4 + 3][m] = v.w;
        }
        for (int i = tid; i < BK * (BN / 4); i += 256) {
            int k = i / (BN / 4), n4 = (i % (BN / 4)) * 4;
            float4 v = *(const float4*)(Bm + (long)(k0 + k) * N + bn + n4);
            Bs[k][n4] = v.x; Bs[k][n4 + 1] = v.y; Bs[k][n4 + 2] = v.z; Bs[k][n4 + 3] = v.w;
        }
        __syncthreads();
#pragma unroll
        for (int kk = 0; kk < BK; ++kk) {
            float a[TM], b[TN];
#pragma unroll
            for (int i = 0; i < TM; i++) a[i] = As[kk][tr * TM + i];
#pragma unroll
            for (int j = 0; j < TN; j++) b[j] = Bs[kk][tc * TN + j];
#pragma unroll
            for (int i = 0; i < TM; i++)
#pragma unroll
                for (int j = 0; j < TN; j++) acc[i][j] += a[i] * b[j];
        }
        __syncthreads();
    }
#pragma unroll
    for (int i = 0; i < TM; i++) {
        int m = bm + tr * TM + i;
#pragma unroll
        for (int j = 0; j < TN; j++) {
            int n = bn + tc * TN + j;
            stout(&C[(long)m * N + n], acc[i][j]);
        }
    }
}

// ---------------------------------------------------------------------------
// Masked softmax over S=256, in place.
// ---------------------------------------------------------------------------
__global__ __launch_bounds__(256) void softmax_mask(
    float* __restrict__ attn, const int* __restrict__ src_len)
{
    __shared__ float red[4];
    const int b = blockIdx.y, t = blockIdx.x, s = threadIdx.x;
    float* row = attn + ((long)b * TT + t) * SS;
    const int L = src_len[b];
    float v = (s < L) ? row[s] : -INFINITY;
    float m = v;
#pragma unroll
    for (int o = 32; o >= 1; o >>= 1) m = fmaxf(m, __shfl_xor(m, o));
    if ((s & 63) == 0) red[s >> 6] = m;
    __syncthreads();
    m = fmaxf(fmaxf(red[0], red[1]), fmaxf(red[2], red[3]));
    __syncthreads();
    float e = (s < L) ? expf(v - m) : 0.0f;
    float sum = e;
#pragma unroll
    for (int o = 32; o >= 1; o >>= 1) sum += __shfl_xor(sum, o);
    if ((s & 63) == 0) red[s >> 6] = sum;
    __syncthreads();
    sum = red[0] + red[1] + red[2] + red[3];
    row[s] = e / sum;
}

// ---------------------------------------------------------------------------
extern "C" void kernel_launch(void* const* d_in, const int* in_sizes, int n_in,
                              void* d_out, int out_size, void* d_ws, size_t ws_size,
                              hipStream_t stream)
{
    const float* trg_emb = (const float*)d_in[0];
    const float* h0      = (const float*)d_in[1];
    const float* c0      = (const float*)d_in[2];
    const float* ctx     = (const float*)d_in[3];
    const int*   src_len = (const int*)d_in[4];
    const float* W_ih    = (const float*)d_in[5];
    const float* W_hh    = (const float*)d_in[6];
    const float* b_ih    = (const float*)d_in[7];
    const float* b_hh    = (const float*)d_in[8];
    const float* W_in    = (const float*)d_in[9];
    const float* W_out   = (const float*)d_in[10];

    float* out = (float*)d_out;
    float* h_tilde = out;                          // [B,T,H]
    float* hT = out + (size_t)BB * TT * HHH;       // [1,B,H]
    float* cT = hT + (size_t)BB * HHH;             // [1,B,H]

    char* w = (char*)d_ws;
    auto take = [&](size_t bytes) { void* p = w; w += (bytes + 255) & ~(size_t)255; return p; };
    // ring (128 slots x 256 KB = 33.55 MB) aliases trg16+Wih16+spare: ring is
    // written only inside lstm_scan6, after the xgt GEMM consumed trg16/Wih16
    // (stream-ordered), so the overlap is safe (scheme proven in r9).
    char* base0 = w;
    u16* trg16  = (u16*)take(8388608ull * 2);      // 16.78 MB
    u16* Wih16  = (u16*)take(4194304ull * 2);      //  8.39 MB
    take(8388608ull);                              //  8.39 MB ring tail spare
    u16* ring   = (u16*)base0;                     // 33.55 MB total
    u16* h0s    = (u16*)take(262144ull);           // frag slot for t=0
    u16* Win16  = (u16*)take(1048576ull * 2);
    u16* Wout16 = (u16*)take(2097152ull * 2);
    u16* lstm16 = (u16*)take(8388608ull * 2);
    u16* WF     = (u16*)take(16777216ull);         // W fragment layout (16.78 MB)
    int* bar    = (int*)take(4096);
    char* regionB = w;
    float* xgt = (float*)take(33554432ull * 4);    // [t][4H r=j*4+g][B] fp32
    float* q        = (float*)regionB;
    float* attn     = (float*)(regionB + 33554432ull);
    u16*   ctxout16 = (u16*)(regionB + 41943040ull);

    // barrier counters must start at 0 every call
    hipMemsetAsync(bar, 0, 4096, stream);

    // prep (independent, parallel)
    f32_to_bf16<<<4096, 256, 0, stream>>>(trg_emb, trg16, 8388608);
    f32_to_bf16<<<2048, 256, 0, stream>>>(W_ih, Wih16, 4194304);
    f32_to_bf16<<<512, 256, 0, stream>>>(W_in, Win16, 1048576);
    f32_to_bf16<<<1024, 256, 0, stream>>>(W_out, Wout16, 2097152);
    wfrag_build<<<dim3(8, 4, 128), 128, 0, stream>>>(W_hh, WF);
    h0frag<<<32, 256, 0, stream>>>(h0, h0s);

    // x_gates = trg_emb @ W_ih^T + (b_ih+b_hh) -> fp32 xgt[t][j*4+g][b]
    gemm_mfma_bt<false, true, float><<<dim3(32, 64), 256, 0, stream>>>(
        trg16, trg16, Wih16, xgt, 8192, 4096, 1024, 1024, b_ih, b_hh);

    // persistent LSTM scan (single launch; writes lstm16, hT, cT)
    lstm_scan6<<<SCANBLK, 512, 0, stream>>>(xgt, WF, c0, h0s, ring,
                                            hT, cT, lstm16, bar);

    // q = lstm_out @ W_in^T (bf16 MFMA, fp32 out)
    gemm_mfma_bt<false, false, float><<<dim3(8, 64), 256, 0, stream>>>(
        lstm16, lstm16, Win16, q, 8192, 1024, 1024, 1024, nullptr, nullptr);

    // scores[b] = q[b] @ ctx[b]^T (fp32)
    gemm_bt<64, 64, 4, 4><<<dim3(4, 2, 64), 256, 0, stream>>>(
        q, ctx, attn, TT, SS, HHH,
        (long)TT * HHH, (long)SS * HHH, (long)TT * SS);

    softmax_mask<<<dim3(TT, BB, 1), 256, 0, stream>>>(attn, src_len);

    // context[b] = attn[b] @ ctx[b] (fp32 compute, bf16 out)
    gemm_bn<64, 64, 4, 4, u16><<<dim3(16, 2, 64), 256, 0, stream>>>(
        attn, ctx, ctxout16, TT, HHH, SS,
        (long)TT * SS, (long)SS * HHH, (long)TT * HHH);

    // h_tilde = tanh([context, lstm_out] @ W_out^T)
    gemm_mfma_bt<true, false, float><<<dim3(8, 64), 256, 0, stream>>>(
        ctxout16, lstm16, Wout16, h_tilde, 8192, 1024, 2048, 1024, nullptr, nullptr);
}

// Round 11
// 1405.907 us; speedup vs baseline: 4.5726x; 1.3892x over previous
//
#include <hip/hip_runtime.h>
#include <math.h>

#define BB 64
#define TT 128
#define SS 256
#define HHH 1024
#define SCANBLK 256

typedef unsigned short u16;
typedef unsigned int u32;
typedef unsigned long long u64t;
typedef __bf16 bf16x8 __attribute__((ext_vector_type(8)));
typedef float f32x4 __attribute__((ext_vector_type(4)));
typedef u16 u16x8 __attribute__((ext_vector_type(8)));

__device__ __forceinline__ float sigmoidf_(float x) { return 1.0f / (1.0f + expf(-x)); }
__device__ __forceinline__ u16 f2bf(float f) {
    __bf16 h = (__bf16)f;
    return __builtin_bit_cast(u16, h);
}
__device__ __forceinline__ float b2f(u16 u) {
    return __builtin_bit_cast(float, (u32)u << 16);
}
template <typename OT>
__device__ __forceinline__ void stout(OT* p, float v) {
    if constexpr (sizeof(OT) == 2) *p = f2bf(v); else *p = v;
}
__device__ __forceinline__ void astore(u64t* p, u64t v) {
    __hip_atomic_store(p, v, __ATOMIC_RELAXED, __HIP_MEMORY_SCOPE_AGENT);
}
__device__ __forceinline__ int afetchadd(int* p) {
    return __hip_atomic_fetch_add(p, 1, __ATOMIC_RELAXED, __HIP_MEMORY_SCOPE_AGENT);
}
__device__ __forceinline__ int aload32(const int* p) {
    return __hip_atomic_load(p, __ATOMIC_RELAXED, __HIP_MEMORY_SCOPE_AGENT);
}
__device__ __forceinline__ void astore32(int* p, int v) {
    __hip_atomic_store(p, v, __ATOMIC_RELAXED, __HIP_MEMORY_SCOPE_AGENT);
}

// ---------------------------------------------------------------------------
// fp32 → bf16 elementwise
// ---------------------------------------------------------------------------
__global__ __launch_bounds__(256) void f32_to_bf16(const float* __restrict__ in,
                                                   u16* __restrict__ out, long n) {
    long i = ((long)blockIdx.x * 256 + threadIdx.x) * 8;
    float4 a = *(const float4*)(in + i);
    float4 b = *(const float4*)(in + i + 4);
    u16x8 o;
    o[0] = f2bf(a.x); o[1] = f2bf(a.y); o[2] = f2bf(a.z); o[3] = f2bf(a.w);
    o[4] = f2bf(b.x); o[5] = f2bf(b.y); o[6] = f2bf(b.z); o[7] = f2bf(b.w);
    *(u16x8*)(out + i) = o;
}

// ---------------------------------------------------------------------------
// W_hh fp32 -> fragment-major split-precision WF (same layout as r10).
// frag_id = (((bid128*4+kq)*8+w)*2+rh)*2+plane ; frag = 64 lanes x 8 u16.
// lane l: W[row' = bid128*32+rh*16+(l&15)][k = kq*256+w*32+(l>>4)*8 .. +8]
// ---------------------------------------------------------------------------
__global__ __launch_bounds__(128) void wfrag_build(const float* __restrict__ W,
                                                   u16* __restrict__ WF) {
    const int w = blockIdx.x, kq = blockIdx.y, bid = blockIdx.z;
    const int t = threadIdx.x;
    const int rh = t >> 6, lane = t & 63;
    const int rowp = bid * 32 + rh * 16 + (lane & 15);
    const int g = rowp & 3, jrow = rowp >> 2;
    const int k = kq * 256 + w * 32 + (lane >> 4) * 8;
    const float* src = W + ((size_t)(g * 1024 + jrow) << 10) + k;
    float4 v0 = *(const float4*)src;
    float4 v1 = *(const float4*)(src + 4);
    float vv[8] = {v0.x, v0.y, v0.z, v0.w, v1.x, v1.y, v1.z, v1.w};
    u16x8 hi, lo;
#pragma unroll
    for (int i = 0; i < 8; ++i) {
        u16 h = f2bf(vv[i]);
        hi[i] = h;
        lo[i] = f2bf(vv[i] - b2f(h));
    }
    size_t fr = ((((size_t)bid * 4 + kq) * 8 + w) * 2 + rh) * 2;
    *(u16x8*)(WF + fr * 512 + (size_t)lane * 8) = hi;
    *(u16x8*)(WF + (fr + 1) * 512 + (size_t)lane * 8) = lo;
}

// ---------------------------------------------------------------------------
// h0 fp32 [64 b][1024 j] -> fragment-major hi/lo slot (t=0 ring input).
// ---------------------------------------------------------------------------
__global__ __launch_bounds__(256) void h0frag(const float* __restrict__ h0,
                                              u16* __restrict__ slot) {
    int i = blockIdx.x * 256 + threadIdx.x;   // 8192 = 64 b x 128 j-groups
    int b = i >> 7, jg = i & 127;
    int j = jg << 3;
    const float* src = h0 + ((size_t)b << 10) + j;
    float4 v0 = *(const float4*)src;
    float4 v1 = *(const float4*)(src + 4);
    float vv[8] = {v0.x, v0.y, v0.z, v0.w, v1.x, v1.y, v1.z, v1.w};
    u16x8 hi, lo;
#pragma unroll
    for (int e = 0; e < 8; ++e) {
        u16 h = f2bf(vv[e]);
        hi[e] = h;
        lo[e] = f2bf(vv[e] - b2f(h));
    }
    int kq = j >> 8, w = (j >> 5) & 7, tr = (j >> 3) & 3;
    int bt = b >> 4, lane = tr * 16 + (b & 15);
    size_t fb = (((size_t)kq * 8 + w) * 4 + bt) * 2;
    *(u16x8*)(slot + fb * 512 + (size_t)lane * 8) = hi;
    *(u16x8*)(slot + (fb + 1) * 512 + (size_t)lane * 8) = lo;
}

// ---------------------------------------------------------------------------
// MFMA bf16 GEMM (A@B^T). XGT mode writes fp32 xgt[t][j*4+g][b] + bias.
// ---------------------------------------------------------------------------
template <bool TANH, bool XGT, typename OT>
__global__ __launch_bounds__(256) void gemm_mfma_bt(
    const u16* __restrict__ A0, const u16* __restrict__ A1,
    const u16* __restrict__ B, OT* __restrict__ C,
    int M, int N, int K, int KA0,
    const float* __restrict__ bias0, const float* __restrict__ bias1)
{
    __shared__ uint4 As4[512];
    __shared__ uint4 Bs4[512];
    u16* As = (u16*)As4;
    u16* Bs = (u16*)Bs4;
    const int tid = threadIdx.x;
    const int l = tid & 63;
    const int w = tid >> 6;
    const int wm = w >> 1, wn = w & 1;
    const int tc = l & 15, tr8 = (l >> 4) << 3;
    const int m0 = blockIdx.y << 7, n0 = blockIdx.x << 7;
    f32x4 acc[4][4] = {};

    for (int k0 = 0; k0 < K; k0 += 32) {
        const u16* Ap = (k0 < KA0) ? A0 : A1;
        const int koff = (k0 < KA0) ? k0 : k0 - KA0;
#pragma unroll
        for (int r = 0; r < 2; ++r) {
            int u = tid + (r << 8);
            int row = u >> 2, q = u & 3;
            size_t arow;
            if (XGT) {
                int rr = m0 + row;
                arow = (size_t)((rr & 63) * 128 + (rr >> 6));
            } else {
                arow = (size_t)(m0 + row);
            }
            As4[u] = *(const uint4*)(Ap + arow * KA0 + koff + (q << 3));
            Bs4[u] = *(const uint4*)(B + (size_t)(n0 + row) * K + k0 + (q << 3));
        }
        __syncthreads();
        bf16x8 bfr[4];
#pragma unroll
        for (int j = 0; j < 4; ++j)
            bfr[j] = *(const bf16x8*)(Bs + ((wn << 6) + (j << 4) + tc) * 32 + tr8);
#pragma unroll
        for (int i = 0; i < 4; ++i) {
            bf16x8 af = *(const bf16x8*)(As + ((wm << 6) + (i << 4) + tc) * 32 + tr8);
#pragma unroll
            for (int j = 0; j < 4; ++j)
                acc[i][j] = __builtin_amdgcn_mfma_f32_16x16x32_bf16(af, bfr[j], acc[i][j], 0, 0, 0);
        }
        __syncthreads();
    }
#pragma unroll
    for (int j = 0; j < 4; ++j) {
        const int col = n0 + (wn << 6) + (j << 4) + tc;
        const float bias = XGT ? (bias0[col] + bias1[col]) : 0.0f;
#pragma unroll
        for (int i = 0; i < 4; ++i) {
#pragma unroll
            for (int v = 0; v < 4; ++v) {
                int r = m0 + (wm << 6) + (i << 4) + ((l >> 4) << 2) + v;
                float val = acc[i][j][v];
                if (XGT) {
                    int newr = ((col & 1023) << 2) | (col >> 10);   // j*4+g
                    ((float*)C)[(size_t)(r >> 6) * 262144 + (size_t)newr * 64 + (r & 63)] = val + bias;
                } else {
                    if (TANH) val = tanhf(val);
                    stout(&C[(size_t)r * N + col], val);
                }
            }
        }
    }
}

// ---------------------------------------------------------------------------
// Persistent LSTM scan v7. 256 blocks x 512 thr (8 waves = 2/SIMD), 128 steps.
// Block owns 4 j x 4 gates = 16 rows; waves = 4 k-quarters x 2 batch-halves.
// W fragments in registers (16 frags = 64 VGPR, same WF layout as r10).
// h ring: frag-major slots; cached frag reads, memory-side 8B atomic writes.
// Hierarchical release barrier: 32 leaves -> root -> gen -> per-leaf leafgen
// (only 32 same-line pollers on gen, 7 on each leafgen).
// xgt for step t+1 prefetched before the barrier.
// Math chain order identical to r9/r10 -> bit-identical output.
// ---------------------------------------------------------------------------
__global__ __launch_bounds__(512) void lstm_scan7(
    const float* __restrict__ xgt, const u16* __restrict__ WF,
    const float* __restrict__ c0,
    const u16* __restrict__ h0s, u16* __restrict__ ring,
    float* __restrict__ hT, float* __restrict__ cT,
    u16* __restrict__ lstm16, int* __restrict__ bar)
{
    __shared__ float red[4][16][68];             // 17.4 KB
    __shared__ __align__(8) u16 tileh[64][4];    // 0.5 KB
    __shared__ __align__(8) u16 tilel[64][4];
    const int tid = threadIdx.x;
    const int bid = blockIdx.x;
    const int kg = tid >> 6, l = tid & 63;
    const int kq = kg & 3, bh = kg >> 2;         // batch half: bt = bh*2 + {0,1}
    const int j0 = bid << 2;                     // 4 j per block
    const int eb = tid & 63;
    const int ej = tid >> 6;                     // 0..3 valid when tid<256

    // W fragments -> registers (rows bid*16 + (l&15); rh = bid&1 of old map)
    bf16x8 wf0[8], wf1[8];
#pragma unroll
    for (int w = 0; w < 8; ++w) {
        size_t fr = (((((size_t)(bid >> 1)) * 4 + kq) * 8 + w) * 2 + (bid & 1)) * 2;
        wf0[w] = *(const bf16x8*)(WF + fr * 512 + (size_t)l * 8);
        wf1[w] = *(const bf16x8*)(WF + (fr + 1) * 512 + (size_t)l * 8);
    }
    float cv = 0.0f;
    if (tid < 256) cv = c0[(size_t)eb * 1024 + j0 + ej];

    // xgt prefetch for t=0
    float xgv[4] = {};
    if (tid < 256) {
#pragma unroll
        for (int g = 0; g < 4; ++g)
            xgv[g] = xgt[(size_t)(((j0 + ej) << 2) + g) * 64 + eb];
    }

    for (int t = 0; t < 128; ++t) {
        const u16* hin = (t == 0) ? h0s : (ring + (size_t)(t - 1) * 131072);
        u16* hout = ring + (size_t)t * 131072;

        f32x4 acc[2] = {};
        bf16x8 hbA[2][2], hbB[2][2];
#define LDW(HB, W)                                                               \
        {                                                                        \
            _Pragma("unroll")                                                    \
            for (int b2 = 0; b2 < 2; ++b2) {                                     \
                size_t fb = (((size_t)kq * 8 + (W)) * 4 + (bh * 2 + b2)) * 2;    \
                HB[b2][0] = *(const bf16x8*)(hin + fb * 512 + (size_t)l * 8);    \
                HB[b2][1] = *(const bf16x8*)(hin + (fb + 1) * 512 + (size_t)l * 8); \
            }                                                                    \
        }
        LDW(hbA, 0)
#pragma unroll
        for (int w = 0; w < 8; w += 2) {
            LDW(hbB, w + 1)
#pragma unroll
            for (int b2 = 0; b2 < 2; ++b2) {
                acc[b2] = __builtin_amdgcn_mfma_f32_16x16x32_bf16(wf0[w], hbA[b2][0], acc[b2], 0, 0, 0);
                acc[b2] = __builtin_amdgcn_mfma_f32_16x16x32_bf16(wf0[w], hbA[b2][1], acc[b2], 0, 0, 0);
                acc[b2] = __builtin_amdgcn_mfma_f32_16x16x32_bf16(wf1[w], hbA[b2][0], acc[b2], 0, 0, 0);
            }
            if (w + 2 < 8) LDW(hbA, w + 2)
#pragma unroll
            for (int b2 = 0; b2 < 2; ++b2) {
                acc[b2] = __builtin_amdgcn_mfma_f32_16x16x32_bf16(wf0[w + 1], hbB[b2][0], acc[b2], 0, 0, 0);
                acc[b2] = __builtin_amdgcn_mfma_f32_16x16x32_bf16(wf0[w + 1], hbB[b2][1], acc[b2], 0, 0, 0);
                acc[b2] = __builtin_amdgcn_mfma_f32_16x16x32_bf16(wf1[w + 1], hbB[b2][0], acc[b2], 0, 0, 0);
            }
        }
#undef LDW

#pragma unroll
        for (int b2 = 0; b2 < 2; ++b2)
#pragma unroll
            for (int v = 0; v < 4; ++v)
                red[kq][((l >> 4) << 2) + v][((bh * 2 + b2) << 4) + (l & 15)] = acc[b2][v];
        __syncthreads();

        // epilogue (tid<256): one (b=eb, j=j0+ej) per thread
        if (tid < 256) {
            float gate[4];
#pragma unroll
            for (int g = 0; g < 4; ++g) {
                int rr = (ej << 2) + g;
                gate[g] = red[0][rr][eb] + red[1][rr][eb] +
                          red[2][rr][eb] + red[3][rr][eb] + xgv[g];
            }
            float ii = sigmoidf_(gate[0]);
            float ff = sigmoidf_(gate[1]);
            float gg = tanhf(gate[2]);
            float oo = sigmoidf_(gate[3]);
            float cn = ff * cv + ii * gg;
            float hn = oo * tanhf(cn);
            cv = cn;
            u16 hh = f2bf(hn);
            tileh[eb][ej] = hh;
            tilel[eb][ej] = f2bf(hn - b2f(hh));
            if (t == 127) {
                hT[(size_t)eb * 1024 + j0 + ej] = hn;
                cT[(size_t)eb * 1024 + j0 + ej] = cn;
            }
        }
        __syncthreads();

        // store phase: frag-layout ring slot (8B atomics) + lstm16
        {
            const int kqb = bid >> 6, wb = (bid >> 3) & 7, trb = (bid >> 1) & 3;
            const int e0 = (bid & 1) * 4;   // u16 offset within lane's 8 elems
            if (tid < 64) {
                int b = tid;
                int bt = b >> 4, lane = trb * 16 + (b & 15);
                size_t fb = (((size_t)kqb * 8 + wb) * 4 + bt) * 2;
                astore((u64t*)(hout + fb * 512 + (size_t)lane * 8 + e0),
                       *(const u64t*)&tileh[b][0]);
                *(u64t*)(lstm16 + ((size_t)b * 128 + t) * 1024 + j0) =
                    *(const u64t*)&tileh[b][0];
            } else if (tid < 128) {
                int b = tid - 64;
                int bt = b >> 4, lane = trb * 16 + (b & 15);
                size_t fb = (((size_t)kqb * 8 + wb) * 4 + bt) * 2 + 1;
                astore((u64t*)(hout + fb * 512 + (size_t)lane * 8 + e0),
                       *(const u64t*)&tilel[b][0]);
            }
        }

        // prefetch next step's xgt (independent of h) before the barrier
        if (t < 127) {
            if (tid < 256) {
#pragma unroll
                for (int g = 0; g < 4; ++g)
                    xgv[g] = xgt[(size_t)(t + 1) * 262144 +
                                 (size_t)(((j0 + ej) << 2) + g) * 64 + eb];
            }
            __syncthreads();   // drains vmem: ring stores memory-side-visible
            if (tid == 0) {
                const int leaf = bid & 31;
                int a = afetchadd(&bar[leaf * 16]);
                if ((a & 7) == 7) {
                    int r = afetchadd(&bar[512]);
                    if ((r & 31) == 31) astore32(&bar[528], t + 1);
                    while (aload32(&bar[528]) < t + 1) __builtin_amdgcn_s_sleep(2);
                    astore32(&bar[544 + leaf * 16], t + 1);
                } else {
                    while (aload32(&bar[544 + leaf * 16]) < t + 1)
                        __builtin_amdgcn_s_sleep(2);
                }
            }
            __syncthreads();
        }
    }
}

// ---------------------------------------------------------------------------
// fp32 GEMM C = A @ B^T (scores), batched via blockIdx.z.
// ---------------------------------------------------------------------------
template <int BM, int BN, int TM, int TN>
__global__ __launch_bounds__(256) void gemm_bt(
    const float* __restrict__ A, const float* __restrict__ Bm, float* __restrict__ C,
    int M, int N, int K, long sA, long sB, long sC)
{
    constexpr int BK = 16;
    __shared__ float As[BK][BM + 1];
    __shared__ float Bs[BK][BN + 1];
    const int z = blockIdx.z;
    A += (long)z * sA; Bm += (long)z * sB; C += (long)z * sC;
    const int bm = blockIdx.y * BM, bn = blockIdx.x * BN;
    const int tid = threadIdx.x;
    constexpr int TC = BN / TN;
    const int tc = tid % TC, tr = tid / TC;
    float acc[TM][TN] = {};
    for (int k0 = 0; k0 < K; k0 += BK) {
        for (int i = tid; i < BM * 4; i += 256) {
            int m = i >> 2, k4 = (i & 3) << 2;
            float4 v = *(const float4*)(A + (long)(bm + m) * K + k0 + k4);
            As[k4][m] = v.x; As[k4 + 1][m] = v.y; As[k4 + 2][m] = v.z; As[k4 + 3][m] = v.w;
        }
        for (int i = tid; i < BN * 4; i += 256) {
            int n = i >> 2, k4 = (i & 3) << 2;
            float4 v = *(const float4*)(Bm + (long)(bn + n) * K + k0 + k4);
            Bs[k4][n] = v.x; Bs[k4 + 1][n] = v.y; Bs[k4 + 2][n] = v.z; Bs[k4 + 3][n] = v.w;
        }
        __syncthreads();
#pragma unroll
        for (int kk = 0; kk < BK; ++kk) {
            float a[TM], b[TN];
#pragma unroll
            for (int i = 0; i < TM; i++) a[i] = As[kk][tr * TM + i];
#pragma unroll
            for (int j = 0; j < TN; j++) b[j] = Bs[kk][tc * TN + j];
#pragma unroll
            for (int i = 0; i < TM; i++)
#pragma unroll
                for (int j = 0; j < TN; j++) acc[i][j] += a[i] * b[j];
        }
        __syncthreads();
    }
#pragma unroll
    for (int i = 0; i < TM; i++) {
        int m = bm + tr * TM + i;
#pragma unroll
        for (int j = 0; j < TN; j++) {
            int n = bn + tc * TN + j;
            C[(long)m * N + n] = acc[i][j];
        }
    }
}

// ---------------------------------------------------------------------------
// fp32 GEMM C = A @ B (context = attn @ ctx), OT output.
// ---------------------------------------------------------------------------
template <int BM, int BN, int TM, int TN, typename OT>
__global__ __launch_bounds__(256) void gemm_bn(
    const float* __restrict__ A, const float* __restrict__ Bm, OT* __restrict__ C,
    int M, int N, int K, long sA, long sB, long sC)
{
    constexpr int BK = 16;
    __shared__ float As[BK][BM + 1];
    __shared__ float Bs[BK][BN + 1];
    const int z = blockIdx.z;
    A += (long)z * sA; Bm += (long)z * sB; C += (long)z * sC;
    const int bm = blockIdx.y * BM, bn = blockIdx.x * BN;
    const int tid = threadIdx.x;
    constexpr int TC = BN / TN;
    const int tc = tid % TC, tr = tid / TC;
    float acc[TM][TN] = {};
    for (int k0 = 0; k0 < K; k0 += BK) {
        for (int i = tid; i < BM * 4; i += 256) {
            int m = i >> 2, k4 = (i & 3) << 2;
            float4 v = *(const float4*)(A + (long)(bm + m) * K + k0 + k4);
            As[k4][m] = v.x; As[k4 + 1][m] = v.y; As[k4 + 2][m] = v.z; As[k4 + 3][m] = v.w;
        }
        for (int i = tid; i < BK * (BN / 4); i += 256) {
            int k = i / (BN / 4), n4 = (i % (BN / 4)) * 4;
            float4 v = *(const float4*)(Bm + (long)(k0 + k) * N + bn + n4);
            Bs[k][n4] = v.x; Bs[k][n4 + 1] = v.y; Bs[k][n4 + 2] = v.z; Bs[k][n4 + 3] = v.w;
        }
        __syncthreads();
#pragma unroll
        for (int kk = 0; kk < BK; ++kk) {
            float a[TM], b[TN];
#pragma unroll
            for (int i = 0; i < TM; i++) a[i] = As[kk][tr * TM + i];
#pragma unroll
            for (int j = 0; j < TN; j++) b[j] = Bs[kk][tc * TN + j];
#pragma unroll
            for (int i = 0; i < TM; i++)
#pragma unroll
                for (int j = 0; j < TN; j++) acc[i][j] += a[i] * b[j];
        }
        __syncthreads();
    }
#pragma unroll
    for (int i = 0; i < TM; i++) {
        int m = bm + tr * TM + i;
#pragma unroll
        for (int j = 0; j < TN; j++) {
            int n = bn + tc * TN + j;
            stout(&C[(long)m * N + n], acc[i][j]);
        }
    }
}

// ---------------------------------------------------------------------------
// Masked softmax over S=256, in place.
// ---------------------------------------------------------------------------
__global__ __launch_bounds__(256) void softmax_mask(
    float* __restrict__ attn, const int* __restrict__ src_len)
{
    __shared__ float red[4];
    const int b = blockIdx.y, t = blockIdx.x, s = threadIdx.x;
    float* row = attn + ((long)b * TT + t) * SS;
    const int L = src_len[b];
    float v = (s < L) ? row[s] : -INFINITY;
    float m = v;
#pragma unroll
    for (int o = 32; o >= 1; o >>= 1) m = fmaxf(m, __shfl_xor(m, o));
    if ((s & 63) == 0) red[s >> 6] = m;
    __syncthreads();
    m = fmaxf(fmaxf(red[0], red[1]), fmaxf(red[2], red[3]));
    __syncthreads();
    float e = (s < L) ? expf(v - m) : 0.0f;
    float sum = e;
#pragma unroll
    for (int o = 32; o >= 1; o >>= 1) sum += __shfl_xor(sum, o);
    if ((s & 63) == 0) red[s >> 6] = sum;
    __syncthreads();
    sum = red[0] + red[1] + red[2] + red[3];
    row[s] = e / sum;
}

// ---------------------------------------------------------------------------
extern "C" void kernel_launch(void* const* d_in, const int* in_sizes, int n_in,
                              void* d_out, int out_size, void* d_ws, size_t ws_size,
                              hipStream_t stream)
{
    const float* trg_emb = (const float*)d_in[0];
    const float* h0      = (const float*)d_in[1];
    const float* c0      = (const float*)d_in[2];
    const float* ctx     = (const float*)d_in[3];
    const int*   src_len = (const int*)d_in[4];
    const float* W_ih    = (const float*)d_in[5];
    const float* W_hh    = (const float*)d_in[6];
    const float* b_ih    = (const float*)d_in[7];
    const float* b_hh    = (const float*)d_in[8];
    const float* W_in    = (const float*)d_in[9];
    const float* W_out   = (const float*)d_in[10];

    float* out = (float*)d_out;
    float* h_tilde = out;                          // [B,T,H]
    float* hT = out + (size_t)BB * TT * HHH;       // [1,B,H]
    float* cT = hT + (size_t)BB * HHH;             // [1,B,H]

    char* w = (char*)d_ws;
    auto take = [&](size_t bytes) { void* p = w; w += (bytes + 255) & ~(size_t)255; return p; };
    // ring (128 slots x 256 KB = 33.55 MB) aliases trg16+Wih16+spare (safe:
    // ring written only inside lstm_scan7, after the xgt GEMM — stream order).
    char* base0 = w;
    u16* trg16  = (u16*)take(8388608ull * 2);      // 16.78 MB
    u16* Wih16  = (u16*)take(4194304ull * 2);      //  8.39 MB
    take(8388608ull);                              //  8.39 MB ring tail spare
    u16* ring   = (u16*)base0;                     // 33.55 MB total
    u16* h0s    = (u16*)take(262144ull);           // frag slot for t=0
    u16* Win16  = (u16*)take(1048576ull * 2);
    u16* Wout16 = (u16*)take(2097152ull * 2);
    u16* lstm16 = (u16*)take(8388608ull * 2);
    u16* WF     = (u16*)take(16777216ull);         // W fragment layout
    int* bar    = (int*)take(8192);
    char* regionB = w;
    float* xgt = (float*)take(33554432ull * 4);    // [t][4H r=j*4+g][B] fp32
    float* q        = (float*)regionB;
    float* attn     = (float*)(regionB + 33554432ull);
    u16*   ctxout16 = (u16*)(regionB + 41943040ull);

    // barrier counters must start at 0 every call
    hipMemsetAsync(bar, 0, 8192, stream);

    // prep (independent, parallel)
    f32_to_bf16<<<4096, 256, 0, stream>>>(trg_emb, trg16, 8388608);
    f32_to_bf16<<<2048, 256, 0, stream>>>(W_ih, Wih16, 4194304);
    f32_to_bf16<<<512, 256, 0, stream>>>(W_in, Win16, 1048576);
    f32_to_bf16<<<1024, 256, 0, stream>>>(W_out, Wout16, 2097152);
    wfrag_build<<<dim3(8, 4, 128), 128, 0, stream>>>(W_hh, WF);
    h0frag<<<32, 256, 0, stream>>>(h0, h0s);

    // x_gates = trg_emb @ W_ih^T + (b_ih+b_hh) -> fp32 xgt[t][j*4+g][b]
    gemm_mfma_bt<false, true, float><<<dim3(32, 64), 256, 0, stream>>>(
        trg16, trg16, Wih16, xgt, 8192, 4096, 1024, 1024, b_ih, b_hh);

    // persistent LSTM scan (single launch; writes lstm16, hT, cT)
    lstm_scan7<<<SCANBLK, 512, 0, stream>>>(xgt, WF, c0, h0s, ring,
                                            hT, cT, lstm16, bar);

    // q = lstm_out @ W_in^T (bf16 MFMA, fp32 out)
    gemm_mfma_bt<false, false, float><<<dim3(8, 64), 256, 0, stream>>>(
        lstm16, lstm16, Win16, q, 8192, 1024, 1024, 1024, nullptr, nullptr);

    // scores[b] = q[b] @ ctx[b]^T (fp32)
    gemm_bt<64, 64, 4, 4><<<dim3(4, 2, 64), 256, 0, stream>>>(
        q, ctx, attn, TT, SS, HHH,
        (long)TT * HHH, (long)SS * HHH, (long)TT * SS);

    softmax_mask<<<dim3(TT, BB, 1), 256, 0, stream>>>(attn, src_len);

    // context[b] = attn[b] @ ctx[b] (fp32 compute, bf16 out)
    gemm_bn<64, 64, 4, 4, u16><<<dim3(16, 2, 64), 256, 0, stream>>>(
        attn, ctx, ctxout16, TT, HHH, SS,
        (long)TT * SS, (long)SS * HHH, (long)TT * HHH);

    // h_tilde = tanh([context, lstm_out] @ W_out^T)
    gemm_mfma_bt<true, false, float><<<dim3(8, 64), 256, 0, stream>>>(
        ctxout16, lstm16, Wout16, h_tilde, 8192, 1024, 2048, 1024, nullptr, nullptr);
}

// Round 12
// 1325.445 us; speedup vs baseline: 4.8501x; 1.0607x over previous
//
#include <hip/hip_runtime.h>
#include <math.h>

#define BB 64
#define TT 128
#define SS 256
#define HHH 1024
#define SCANBLK 256

typedef unsigned short u16;
typedef unsigned int u32;
typedef unsigned long long u64t;
typedef __bf16 bf16x8 __attribute__((ext_vector_type(8)));
typedef float f32x4 __attribute__((ext_vector_type(4)));
typedef u16 u16x8 __attribute__((ext_vector_type(8)));

__device__ __forceinline__ float sigmoidf_(float x) { return 1.0f / (1.0f + expf(-x)); }
__device__ __forceinline__ u16 f2bf(float f) {
    __bf16 h = (__bf16)f;
    return __builtin_bit_cast(u16, h);
}
__device__ __forceinline__ float b2f(u16 u) {
    return __builtin_bit_cast(float, (u32)u << 16);
}
template <typename OT>
__device__ __forceinline__ void stout(OT* p, float v) {
    if constexpr (sizeof(OT) == 2) *p = f2bf(v); else *p = v;
}
__device__ __forceinline__ void astore(u64t* p, u64t v) {
    __hip_atomic_store(p, v, __ATOMIC_RELAXED, __HIP_MEMORY_SCOPE_AGENT);
}
__device__ __forceinline__ int afetchadd(int* p) {
    return __hip_atomic_fetch_add(p, 1, __ATOMIC_RELAXED, __HIP_MEMORY_SCOPE_AGENT);
}
__device__ __forceinline__ int aload32(const int* p) {
    return __hip_atomic_load(p, __ATOMIC_RELAXED, __HIP_MEMORY_SCOPE_AGENT);
}
__device__ __forceinline__ void astore32(int* p, int v) {
    __hip_atomic_store(p, v, __ATOMIC_RELAXED, __HIP_MEMORY_SCOPE_AGENT);
}

// ---------------------------------------------------------------------------
// fp32 → bf16 elementwise
// ---------------------------------------------------------------------------
__global__ __launch_bounds__(256) void f32_to_bf16(const float* __restrict__ in,
                                                   u16* __restrict__ out, long n) {
    long i = ((long)blockIdx.x * 256 + threadIdx.x) * 8;
    float4 a = *(const float4*)(in + i);
    float4 b = *(const float4*)(in + i + 4);
    u16x8 o;
    o[0] = f2bf(a.x); o[1] = f2bf(a.y); o[2] = f2bf(a.z); o[3] = f2bf(a.w);
    o[4] = f2bf(b.x); o[5] = f2bf(b.y); o[6] = f2bf(b.z); o[7] = f2bf(b.w);
    *(u16x8*)(out + i) = o;
}

// ---------------------------------------------------------------------------
// W_hh fp32 -> fragment-major split-precision WF (same layout as r10/r11).
// ---------------------------------------------------------------------------
__global__ __launch_bounds__(128) void wfrag_build(const float* __restrict__ W,
                                                   u16* __restrict__ WF) {
    const int w = blockIdx.x, kq = blockIdx.y, bid = blockIdx.z;
    const int t = threadIdx.x;
    const int rh = t >> 6, lane = t & 63;
    const int rowp = bid * 32 + rh * 16 + (lane & 15);
    const int g = rowp & 3, jrow = rowp >> 2;
    const int k = kq * 256 + w * 32 + (lane >> 4) * 8;
    const float* src = W + ((size_t)(g * 1024 + jrow) << 10) + k;
    float4 v0 = *(const float4*)src;
    float4 v1 = *(const float4*)(src + 4);
    float vv[8] = {v0.x, v0.y, v0.z, v0.w, v1.x, v1.y, v1.z, v1.w};
    u16x8 hi, lo;
#pragma unroll
    for (int i = 0; i < 8; ++i) {
        u16 h = f2bf(vv[i]);
        hi[i] = h;
        lo[i] = f2bf(vv[i] - b2f(h));
    }
    size_t fr = ((((size_t)bid * 4 + kq) * 8 + w) * 2 + rh) * 2;
    *(u16x8*)(WF + fr * 512 + (size_t)lane * 8) = hi;
    *(u16x8*)(WF + (fr + 1) * 512 + (size_t)lane * 8) = lo;
}

// ---------------------------------------------------------------------------
// h0 fp32 [64 b][1024 j] -> fragment-major hi/lo slot (t=0 ring input).
// ---------------------------------------------------------------------------
__global__ __launch_bounds__(256) void h0frag(const float* __restrict__ h0,
                                              u16* __restrict__ slot) {
    int i = blockIdx.x * 256 + threadIdx.x;   // 8192 = 64 b x 128 j-groups
    int b = i >> 7, jg = i & 127;
    int j = jg << 3;
    const float* src = h0 + ((size_t)b << 10) + j;
    float4 v0 = *(const float4*)src;
    float4 v1 = *(const float4*)(src + 4);
    float vv[8] = {v0.x, v0.y, v0.z, v0.w, v1.x, v1.y, v1.z, v1.w};
    u16x8 hi, lo;
#pragma unroll
    for (int e = 0; e < 8; ++e) {
        u16 h = f2bf(vv[e]);
        hi[e] = h;
        lo[e] = f2bf(vv[e] - b2f(h));
    }
    int kq = j >> 8, w = (j >> 5) & 7, tr = (j >> 3) & 3;
    int bt = b >> 4, lane = tr * 16 + (b & 15);
    size_t fb = (((size_t)kq * 8 + w) * 4 + bt) * 2;
    *(u16x8*)(slot + fb * 512 + (size_t)lane * 8) = hi;
    *(u16x8*)(slot + (fb + 1) * 512 + (size_t)lane * 8) = lo;
}

// ---------------------------------------------------------------------------
// MFMA bf16 GEMM (A@B^T). XGT mode writes fp32 xgt[t][j*4+g][b] + bias.
// ---------------------------------------------------------------------------
template <bool TANH, bool XGT, typename OT>
__global__ __launch_bounds__(256) void gemm_mfma_bt(
    const u16* __restrict__ A0, const u16* __restrict__ A1,
    const u16* __restrict__ B, OT* __restrict__ C,
    int M, int N, int K, int KA0,
    const float* __restrict__ bias0, const float* __restrict__ bias1)
{
    __shared__ uint4 As4[512];
    __shared__ uint4 Bs4[512];
    u16* As = (u16*)As4;
    u16* Bs = (u16*)Bs4;
    const int tid = threadIdx.x;
    const int l = tid & 63;
    const int w = tid >> 6;
    const int wm = w >> 1, wn = w & 1;
    const int tc = l & 15, tr8 = (l >> 4) << 3;
    const int m0 = blockIdx.y << 7, n0 = blockIdx.x << 7;
    f32x4 acc[4][4] = {};

    for (int k0 = 0; k0 < K; k0 += 32) {
        const u16* Ap = (k0 < KA0) ? A0 : A1;
        const int koff = (k0 < KA0) ? k0 : k0 - KA0;
#pragma unroll
        for (int r = 0; r < 2; ++r) {
            int u = tid + (r << 8);
            int row = u >> 2, q = u & 3;
            size_t arow;
            if (XGT) {
                int rr = m0 + row;
                arow = (size_t)((rr & 63) * 128 + (rr >> 6));
            } else {
                arow = (size_t)(m0 + row);
            }
            As4[u] = *(const uint4*)(Ap + arow * KA0 + koff + (q << 3));
            Bs4[u] = *(const uint4*)(B + (size_t)(n0 + row) * K + k0 + (q << 3));
        }
        __syncthreads();
        bf16x8 bfr[4];
#pragma unroll
        for (int j = 0; j < 4; ++j)
            bfr[j] = *(const bf16x8*)(Bs + ((wn << 6) + (j << 4) + tc) * 32 + tr8);
#pragma unroll
        for (int i = 0; i < 4; ++i) {
            bf16x8 af = *(const bf16x8*)(As + ((wm << 6) + (i << 4) + tc) * 32 + tr8);
#pragma unroll
            for (int j = 0; j < 4; ++j)
                acc[i][j] = __builtin_amdgcn_mfma_f32_16x16x32_bf16(af, bfr[j], acc[i][j], 0, 0, 0);
        }
        __syncthreads();
    }
#pragma unroll
    for (int j = 0; j < 4; ++j) {
        const int col = n0 + (wn << 6) + (j << 4) + tc;
        const float bias = XGT ? (bias0[col] + bias1[col]) : 0.0f;
#pragma unroll
        for (int i = 0; i < 4; ++i) {
#pragma unroll
            for (int v = 0; v < 4; ++v) {
                int r = m0 + (wm << 6) + (i << 4) + ((l >> 4) << 2) + v;
                float val = acc[i][j][v];
                if (XGT) {
                    int newr = ((col & 1023) << 2) | (col >> 10);   // j*4+g
                    ((float*)C)[(size_t)(r >> 6) * 262144 + (size_t)newr * 64 + (r & 63)] = val + bias;
                } else {
                    if (TANH) val = tanhf(val);
                    stout(&C[(size_t)r * N + col], val);
                }
            }
        }
    }
}

// ---------------------------------------------------------------------------
// Persistent LSTM scan v7 (unchanged from r11).
// ---------------------------------------------------------------------------
__global__ __launch_bounds__(512) void lstm_scan7(
    const float* __restrict__ xgt, const u16* __restrict__ WF,
    const float* __restrict__ c0,
    const u16* __restrict__ h0s, u16* __restrict__ ring,
    float* __restrict__ hT, float* __restrict__ cT,
    u16* __restrict__ lstm16, int* __restrict__ bar)
{
    __shared__ float red[4][16][68];
    __shared__ __align__(8) u16 tileh[64][4];
    __shared__ __align__(8) u16 tilel[64][4];
    const int tid = threadIdx.x;
    const int bid = blockIdx.x;
    const int kg = tid >> 6, l = tid & 63;
    const int kq = kg & 3, bh = kg >> 2;
    const int j0 = bid << 2;
    const int eb = tid & 63;
    const int ej = tid >> 6;

    bf16x8 wf0[8], wf1[8];
#pragma unroll
    for (int w = 0; w < 8; ++w) {
        size_t fr = (((((size_t)(bid >> 1)) * 4 + kq) * 8 + w) * 2 + (bid & 1)) * 2;
        wf0[w] = *(const bf16x8*)(WF + fr * 512 + (size_t)l * 8);
        wf1[w] = *(const bf16x8*)(WF + (fr + 1) * 512 + (size_t)l * 8);
    }
    float cv = 0.0f;
    if (tid < 256) cv = c0[(size_t)eb * 1024 + j0 + ej];

    float xgv[4] = {};
    if (tid < 256) {
#pragma unroll
        for (int g = 0; g < 4; ++g)
            xgv[g] = xgt[(size_t)(((j0 + ej) << 2) + g) * 64 + eb];
    }

    for (int t = 0; t < 128; ++t) {
        const u16* hin = (t == 0) ? h0s : (ring + (size_t)(t - 1) * 131072);
        u16* hout = ring + (size_t)t * 131072;

        f32x4 acc[2] = {};
        bf16x8 hbA[2][2], hbB[2][2];
#define LDW(HB, W)                                                               \
        {                                                                        \
            _Pragma("unroll")                                                    \
            for (int b2 = 0; b2 < 2; ++b2) {                                     \
                size_t fb = (((size_t)kq * 8 + (W)) * 4 + (bh * 2 + b2)) * 2;    \
                HB[b2][0] = *(const bf16x8*)(hin + fb * 512 + (size_t)l * 8);    \
                HB[b2][1] = *(const bf16x8*)(hin + (fb + 1) * 512 + (size_t)l * 8); \
            }                                                                    \
        }
        LDW(hbA, 0)
#pragma unroll
        for (int w = 0; w < 8; w += 2) {
            LDW(hbB, w + 1)
#pragma unroll
            for (int b2 = 0; b2 < 2; ++b2) {
                acc[b2] = __builtin_amdgcn_mfma_f32_16x16x32_bf16(wf0[w], hbA[b2][0], acc[b2], 0, 0, 0);
                acc[b2] = __builtin_amdgcn_mfma_f32_16x16x32_bf16(wf0[w], hbA[b2][1], acc[b2], 0, 0, 0);
                acc[b2] = __builtin_amdgcn_mfma_f32_16x16x32_bf16(wf1[w], hbA[b2][0], acc[b2], 0, 0, 0);
            }
            if (w + 2 < 8) LDW(hbA, w + 2)
#pragma unroll
            for (int b2 = 0; b2 < 2; ++b2) {
                acc[b2] = __builtin_amdgcn_mfma_f32_16x16x32_bf16(wf0[w + 1], hbB[b2][0], acc[b2], 0, 0, 0);
                acc[b2] = __builtin_amdgcn_mfma_f32_16x16x32_bf16(wf0[w + 1], hbB[b2][1], acc[b2], 0, 0, 0);
                acc[b2] = __builtin_amdgcn_mfma_f32_16x16x32_bf16(wf1[w + 1], hbB[b2][0], acc[b2], 0, 0, 0);
            }
        }
#undef LDW

#pragma unroll
        for (int b2 = 0; b2 < 2; ++b2)
#pragma unroll
            for (int v = 0; v < 4; ++v)
                red[kq][((l >> 4) << 2) + v][((bh * 2 + b2) << 4) + (l & 15)] = acc[b2][v];
        __syncthreads();

        if (tid < 256) {
            float gate[4];
#pragma unroll
            for (int g = 0; g < 4; ++g) {
                int rr = (ej << 2) + g;
                gate[g] = red[0][rr][eb] + red[1][rr][eb] +
                          red[2][rr][eb] + red[3][rr][eb] + xgv[g];
            }
            float ii = sigmoidf_(gate[0]);
            float ff = sigmoidf_(gate[1]);
            float gg = tanhf(gate[2]);
            float oo = sigmoidf_(gate[3]);
            float cn = ff * cv + ii * gg;
            float hn = oo * tanhf(cn);
            cv = cn;
            u16 hh = f2bf(hn);
            tileh[eb][ej] = hh;
            tilel[eb][ej] = f2bf(hn - b2f(hh));
            if (t == 127) {
                hT[(size_t)eb * 1024 + j0 + ej] = hn;
                cT[(size_t)eb * 1024 + j0 + ej] = cn;
            }
        }
        __syncthreads();

        {
            const int kqb = bid >> 6, wb = (bid >> 3) & 7, trb = (bid >> 1) & 3;
            const int e0 = (bid & 1) * 4;
            if (tid < 64) {
                int b = tid;
                int bt = b >> 4, lane = trb * 16 + (b & 15);
                size_t fb = (((size_t)kqb * 8 + wb) * 4 + bt) * 2;
                astore((u64t*)(hout + fb * 512 + (size_t)lane * 8 + e0),
                       *(const u64t*)&tileh[b][0]);
                *(u64t*)(lstm16 + ((size_t)b * 128 + t) * 1024 + j0) =
                    *(const u64t*)&tileh[b][0];
            } else if (tid < 128) {
                int b = tid - 64;
                int bt = b >> 4, lane = trb * 16 + (b & 15);
                size_t fb = (((size_t)kqb * 8 + wb) * 4 + bt) * 2 + 1;
                astore((u64t*)(hout + fb * 512 + (size_t)lane * 8 + e0),
                       *(const u64t*)&tilel[b][0]);
            }
        }

        if (t < 127) {
            if (tid < 256) {
#pragma unroll
                for (int g = 0; g < 4; ++g)
                    xgv[g] = xgt[(size_t)(t + 1) * 262144 +
                                 (size_t)(((j0 + ej) << 2) + g) * 64 + eb];
            }
            __syncthreads();
            if (tid == 0) {
                const int leaf = bid & 31;
                int a = afetchadd(&bar[leaf * 16]);
                if ((a & 7) == 7) {
                    int r = afetchadd(&bar[512]);
                    if ((r & 31) == 31) astore32(&bar[528], t + 1);
                    while (aload32(&bar[528]) < t + 1) __builtin_amdgcn_s_sleep(2);
                    astore32(&bar[544 + leaf * 16], t + 1);
                } else {
                    while (aload32(&bar[544 + leaf * 16]) < t + 1)
                        __builtin_amdgcn_s_sleep(2);
                }
            }
            __syncthreads();
        }
    }
}

// ---------------------------------------------------------------------------
// scores[b] = q[b] @ ctx[b]^T  via split-precision MFMA (fp32-equivalent).
// q fp32 [b][128][1024], ctx fp32 [b][256][1024]; hi/lo split in-staging.
// Tile 128x128 (M = full T), grid (2, 1, 64). Output fp32 [b][128][256].
// ---------------------------------------------------------------------------
__global__ __launch_bounds__(256) void scores_mfma(
    const float* __restrict__ q, const float* __restrict__ ctx,
    float* __restrict__ C)
{
    __shared__ u16 Ahi[4096], Alo[4096], Bhi[4096], Blo[4096];   // 32 KB
    const int tid = threadIdx.x;
    const int l = tid & 63, w = tid >> 6;
    const int wm = w >> 1, wn = w & 1;
    const int tc = l & 15, tr8 = (l >> 4) << 3;
    const int b = blockIdx.z, n0 = blockIdx.x << 7;
    const float* A = q + (size_t)b * 131072;
    const float* B = ctx + (size_t)b * 262144;
    f32x4 acc[4][4] = {};

    for (int k0 = 0; k0 < 1024; k0 += 32) {
#pragma unroll
        for (int r = 0; r < 4; ++r) {
            int flat = r * 256 + tid;
            int row = flat >> 3, kq = (flat & 7) << 2;
            int o = row * 32 + kq;
            float4 va = *(const float4*)(A + (size_t)row * 1024 + k0 + kq);
            u16 a0 = f2bf(va.x), a1 = f2bf(va.y), a2 = f2bf(va.z), a3 = f2bf(va.w);
            *(ushort4*)&Ahi[o] = (ushort4){a0, a1, a2, a3};
            *(ushort4*)&Alo[o] = (ushort4){f2bf(va.x - b2f(a0)), f2bf(va.y - b2f(a1)),
                                           f2bf(va.z - b2f(a2)), f2bf(va.w - b2f(a3))};
            float4 vb = *(const float4*)(B + (size_t)(n0 + row) * 1024 + k0 + kq);
            u16 g0 = f2bf(vb.x), g1 = f2bf(vb.y), g2 = f2bf(vb.z), g3 = f2bf(vb.w);
            *(ushort4*)&Bhi[o] = (ushort4){g0, g1, g2, g3};
            *(ushort4*)&Blo[o] = (ushort4){f2bf(vb.x - b2f(g0)), f2bf(vb.y - b2f(g1)),
                                           f2bf(vb.z - b2f(g2)), f2bf(vb.w - b2f(g3))};
        }
        __syncthreads();
        bf16x8 bh[4], bl[4];
#pragma unroll
        for (int j = 0; j < 4; ++j) {
            int o = ((wn << 6) + (j << 4) + tc) * 32 + tr8;
            bh[j] = *(const bf16x8*)(Bhi + o);
            bl[j] = *(const bf16x8*)(Blo + o);
        }
#pragma unroll
        for (int i = 0; i < 4; ++i) {
            int o = ((wm << 6) + (i << 4) + tc) * 32 + tr8;
            bf16x8 ah = *(const bf16x8*)(Ahi + o);
            bf16x8 al = *(const bf16x8*)(Alo + o);
#pragma unroll
            for (int j = 0; j < 4; ++j) {
                acc[i][j] = __builtin_amdgcn_mfma_f32_16x16x32_bf16(ah, bh[j], acc[i][j], 0, 0, 0);
                acc[i][j] = __builtin_amdgcn_mfma_f32_16x16x32_bf16(ah, bl[j], acc[i][j], 0, 0, 0);
                acc[i][j] = __builtin_amdgcn_mfma_f32_16x16x32_bf16(al, bh[j], acc[i][j], 0, 0, 0);
            }
        }
        __syncthreads();
    }
#pragma unroll
    for (int j = 0; j < 4; ++j) {
        int col = n0 + (wn << 6) + (j << 4) + tc;
#pragma unroll
        for (int i = 0; i < 4; ++i)
#pragma unroll
            for (int v = 0; v < 4; ++v) {
                int r = (wm << 6) + (i << 4) + ((l >> 4) << 2) + v;
                C[(size_t)b * 32768 + (size_t)r * 256 + col] = acc[i][j][v];
            }
    }
}

// ---------------------------------------------------------------------------
// Masked softmax over S=256; reads fp32 scores, writes bf16 attn.
// (attn in [0,1]; single-bf16 weights add ~5e-4 to context — negligible.)
// ---------------------------------------------------------------------------
__global__ __launch_bounds__(256) void softmax_mask16(
    const float* __restrict__ scores, const int* __restrict__ src_len,
    u16* __restrict__ attn16)
{
    __shared__ float red[4];
    const int b = blockIdx.y, t = blockIdx.x, s = threadIdx.x;
    const float* row = scores + ((long)b * TT + t) * SS;
    const int L = src_len[b];
    float v = (s < L) ? row[s] : -INFINITY;
    float m = v;
#pragma unroll
    for (int o = 32; o >= 1; o >>= 1) m = fmaxf(m, __shfl_xor(m, o));
    if ((s & 63) == 0) red[s >> 6] = m;
    __syncthreads();
    m = fmaxf(fmaxf(red[0], red[1]), fmaxf(red[2], red[3]));
    __syncthreads();
    float e = (s < L) ? expf(v - m) : 0.0f;
    float sum = e;
#pragma unroll
    for (int o = 32; o >= 1; o >>= 1) sum += __shfl_xor(sum, o);
    if ((s & 63) == 0) red[s >> 6] = sum;
    __syncthreads();
    sum = red[0] + red[1] + red[2] + red[3];
    attn16[((long)b * TT + t) * SS + s] = f2bf(e / sum);
}

// ---------------------------------------------------------------------------
// context[b] = attn[b] @ ctx[b]  via bf16 MFMA.
// A = attn16 [128][256] (K=s contiguous); B staged from fp32 ctx [s][h] with
// in-LDS transpose to [h][s] bf16 (pad 40 -> 16B-aligned frag reads).
// Tile 128x128, grid (8, 1, 64). Output bf16 ctxout16 [b*128+t][1024].
// ---------------------------------------------------------------------------
__global__ __launch_bounds__(256) void ctxattn_mfma(
    const u16* __restrict__ attn16, const float* __restrict__ ctx,
    u16* __restrict__ ctxout16)
{
    __shared__ u16 As[4096];          // [t][s-chunk 32]
    __shared__ u16 Bs[128][40];       // [h][s-chunk 32] transposed, padded
    const int tid = threadIdx.x;
    const int l = tid & 63, w = tid >> 6;
    const int wm = w >> 1, wn = w & 1;
    const int tc = l & 15, tr8 = (l >> 4) << 3;
    const int b = blockIdx.z, n0 = blockIdx.x << 7;
    f32x4 acc[4][4] = {};

    for (int k0 = 0; k0 < 256; k0 += 32) {
        {   // A staging: 128 rows x 32 u16 = 8 KB (2 x uint4 per thread)
            int row = tid >> 1, off = (tid & 1) << 4;
            const u16* src = attn16 + (size_t)b * 32768 + (size_t)row * 256 + k0 + off;
            *(uint4*)&As[row * 32 + off] = *(const uint4*)src;
            *(uint4*)&As[row * 32 + off + 8] = *(const uint4*)(src + 8);
        }
#pragma unroll
        for (int p = 0; p < 4; ++p) {   // B transpose staging (fp32 -> bf16)
            int flat = p * 256 + tid;
            int s = flat >> 5, hc = flat & 31;
            float4 v = *(const float4*)(ctx + (size_t)b * 262144 +
                                        (size_t)(k0 + s) * 1024 + n0 + (hc << 2));
            Bs[(hc << 2) + 0][s] = f2bf(v.x);
            Bs[(hc << 2) + 1][s] = f2bf(v.y);
            Bs[(hc << 2) + 2][s] = f2bf(v.z);
            Bs[(hc << 2) + 3][s] = f2bf(v.w);
        }
        __syncthreads();
        bf16x8 bfr[4];
#pragma unroll
        for (int j = 0; j < 4; ++j)
            bfr[j] = *(const bf16x8*)&Bs[(wn << 6) + (j << 4) + tc][tr8];
#pragma unroll
        for (int i = 0; i < 4; ++i) {
            bf16x8 af = *(const bf16x8*)(As + ((wm << 6) + (i << 4) + tc) * 32 + tr8);
#pragma unroll
            for (int j = 0; j < 4; ++j)
                acc[i][j] = __builtin_amdgcn_mfma_f32_16x16x32_bf16(af, bfr[j], acc[i][j], 0, 0, 0);
        }
        __syncthreads();
    }
#pragma unroll
    for (int j = 0; j < 4; ++j) {
        int col = n0 + (wn << 6) + (j << 4) + tc;
#pragma unroll
        for (int i = 0; i < 4; ++i)
#pragma unroll
            for (int v = 0; v < 4; ++v) {
                int r = (wm << 6) + (i << 4) + ((l >> 4) << 2) + v;
                ctxout16[((size_t)b * 128 + r) * 1024 + col] = f2bf(acc[i][j][v]);
            }
    }
}

// ---------------------------------------------------------------------------
extern "C" void kernel_launch(void* const* d_in, const int* in_sizes, int n_in,
                              void* d_out, int out_size, void* d_ws, size_t ws_size,
                              hipStream_t stream)
{
    const float* trg_emb = (const float*)d_in[0];
    const float* h0      = (const float*)d_in[1];
    const float* c0      = (const float*)d_in[2];
    const float* ctx     = (const float*)d_in[3];
    const int*   src_len = (const int*)d_in[4];
    const float* W_ih    = (const float*)d_in[5];
    const float* W_hh    = (const float*)d_in[6];
    const float* b_ih    = (const float*)d_in[7];
    const float* b_hh    = (const float*)d_in[8];
    const float* W_in    = (const float*)d_in[9];
    const float* W_out   = (const float*)d_in[10];

    float* out = (float*)d_out;
    float* h_tilde = out;                          // [B,T,H]
    float* hT = out + (size_t)BB * TT * HHH;       // [1,B,H]
    float* cT = hT + (size_t)BB * HHH;             // [1,B,H]

    char* w = (char*)d_ws;
    auto take = [&](size_t bytes) { void* p = w; w += (bytes + 255) & ~(size_t)255; return p; };
    // ring (128 slots x 256 KB = 33.55 MB) aliases trg16+Wih16+spare (safe:
    // ring written only inside lstm_scan7, after the xgt GEMM — stream order).
    char* base0 = w;
    u16* trg16  = (u16*)take(8388608ull * 2);      // 16.78 MB
    u16* Wih16  = (u16*)take(4194304ull * 2);      //  8.39 MB
    take(8388608ull);                              //  8.39 MB ring tail spare
    u16* ring   = (u16*)base0;                     // 33.55 MB total
    u16* h0s    = (u16*)take(262144ull);           // frag slot for t=0
    u16* Win16  = (u16*)take(1048576ull * 2);
    u16* Wout16 = (u16*)take(2097152ull * 2);
    u16* lstm16 = (u16*)take(8388608ull * 2);
    u16* WF     = (u16*)take(16777216ull);         // W fragment layout
    int* bar    = (int*)take(8192);
    char* regionB = w;
    float* xgt = (float*)take(33554432ull * 4);    // [t][4H r=j*4+g][B] fp32
    // region C aliases region B (xgt dead after the scan):
    float* q        = (float*)regionB;                          // 33.55 MB
    float* scores   = (float*)(regionB + 33554432ull);          //  8.39 MB
    u16*   attn16   = (u16*)(regionB + 41943040ull);            //  4.19 MB
    u16*   ctxout16 = (u16*)(regionB + 46137344ull);            // 16.78 MB

    // barrier counters must start at 0 every call
    hipMemsetAsync(bar, 0, 8192, stream);

    // prep (independent, parallel)
    f32_to_bf16<<<4096, 256, 0, stream>>>(trg_emb, trg16, 8388608);
    f32_to_bf16<<<2048, 256, 0, stream>>>(W_ih, Wih16, 4194304);
    f32_to_bf16<<<512, 256, 0, stream>>>(W_in, Win16, 1048576);
    f32_to_bf16<<<1024, 256, 0, stream>>>(W_out, Wout16, 2097152);
    wfrag_build<<<dim3(8, 4, 128), 128, 0, stream>>>(W_hh, WF);
    h0frag<<<32, 256, 0, stream>>>(h0, h0s);

    // x_gates = trg_emb @ W_ih^T + (b_ih+b_hh) -> fp32 xgt[t][j*4+g][b]
    gemm_mfma_bt<false, true, float><<<dim3(32, 64), 256, 0, stream>>>(
        trg16, trg16, Wih16, xgt, 8192, 4096, 1024, 1024, b_ih, b_hh);

    // persistent LSTM scan (single launch; writes lstm16, hT, cT)
    lstm_scan7<<<SCANBLK, 512, 0, stream>>>(xgt, WF, c0, h0s, ring,
                                            hT, cT, lstm16, bar);

    // q = lstm_out @ W_in^T (bf16 MFMA, fp32 out)
    gemm_mfma_bt<false, false, float><<<dim3(8, 64), 256, 0, stream>>>(
        lstm16, lstm16, Win16, q, 8192, 1024, 1024, 1024, nullptr, nullptr);

    // scores[b] = q[b] @ ctx[b]^T (split-precision MFMA, fp32-equivalent)
    scores_mfma<<<dim3(2, 1, 64), 256, 0, stream>>>(q, ctx, scores);

    // masked softmax -> bf16 attention weights
    softmax_mask16<<<dim3(TT, BB, 1), 256, 0, stream>>>(scores, src_len, attn16);

    // context[b] = attn[b] @ ctx[b] (bf16 MFMA, bf16 out)
    ctxattn_mfma<<<dim3(8, 1, 64), 256, 0, stream>>>(attn16, ctx, ctxout16);

    // h_tilde = tanh([context, lstm_out] @ W_out^T)
    gemm_mfma_bt<true, false, float><<<dim3(8, 64), 256, 0, stream>>>(
        ctxout16, lstm16, Wout16, h_tilde, 8192, 1024, 2048, 1024, nullptr, nullptr);
}

// Round 13
// 1004.377 us; speedup vs baseline: 6.4006x; 1.3197x over previous
//
#include <hip/hip_runtime.h>
#include <math.h>

#define BB 64
#define TT 128
#define SS 256
#define HHH 1024

typedef unsigned short u16;
typedef unsigned int u32;
typedef unsigned long long u64t;
typedef __bf16 bf16x8 __attribute__((ext_vector_type(8)));
typedef float f32x4 __attribute__((ext_vector_type(4)));
typedef u16 u16x8 __attribute__((ext_vector_type(8)));

__device__ __forceinline__ float sigmoidf_(float x) { return 1.0f / (1.0f + expf(-x)); }
__device__ __forceinline__ u16 f2bf(float f) {
    __bf16 h = (__bf16)f;
    return __builtin_bit_cast(u16, h);
}
__device__ __forceinline__ float b2f(u16 u) {
    return __builtin_bit_cast(float, (u32)u << 16);
}
template <typename OT>
__device__ __forceinline__ void stout(OT* p, float v) {
    if constexpr (sizeof(OT) == 2) *p = f2bf(v); else *p = v;
}
__device__ __forceinline__ void astore(u64t* p, u64t v) {
    __hip_atomic_store(p, v, __ATOMIC_RELAXED, __HIP_MEMORY_SCOPE_AGENT);
}
__device__ __forceinline__ int afetchadd(int* p) {
    return __hip_atomic_fetch_add(p, 1, __ATOMIC_RELAXED, __HIP_MEMORY_SCOPE_AGENT);
}
__device__ __forceinline__ int aload32(const int* p) {
    return __hip_atomic_load(p, __ATOMIC_RELAXED, __HIP_MEMORY_SCOPE_AGENT);
}
__device__ __forceinline__ void astore32(int* p, int v) {
    __hip_atomic_store(p, v, __ATOMIC_RELAXED, __HIP_MEMORY_SCOPE_AGENT);
}
// async global->LDS 16B copy (dest must be wave-uniform base + lane*16)
#define GLOAD16(gsrc, ldst)                                                      \
    __builtin_amdgcn_global_load_lds(                                            \
        (const __attribute__((address_space(1))) unsigned int*)(const void*)(gsrc), \
        (__attribute__((address_space(3))) unsigned int*)(void*)(ldst), 16, 0, 0)

// ---------------------------------------------------------------------------
// fp32 → bf16 elementwise
// ---------------------------------------------------------------------------
__global__ __launch_bounds__(256) void f32_to_bf16(const float* __restrict__ in,
                                                   u16* __restrict__ out, long n) {
    long i = ((long)blockIdx.x * 256 + threadIdx.x) * 8;
    float4 a = *(const float4*)(in + i);
    float4 b = *(const float4*)(in + i + 4);
    u16x8 o;
    o[0] = f2bf(a.x); o[1] = f2bf(a.y); o[2] = f2bf(a.z); o[3] = f2bf(a.w);
    o[4] = f2bf(b.x); o[5] = f2bf(b.y); o[6] = f2bf(b.z); o[7] = f2bf(b.w);
    *(u16x8*)(out + i) = o;
}

// ---------------------------------------------------------------------------
// W_hh fp32 -> fragment-major split-precision WF (same layout as r10-r12).
// ---------------------------------------------------------------------------
__global__ __launch_bounds__(128) void wfrag_build(const float* __restrict__ W,
                                                   u16* __restrict__ WF) {
    const int w = blockIdx.x, kq = blockIdx.y, bid = blockIdx.z;
    const int t = threadIdx.x;
    const int rh = t >> 6, lane = t & 63;
    const int rowp = bid * 32 + rh * 16 + (lane & 15);
    const int g = rowp & 3, jrow = rowp >> 2;
    const int k = kq * 256 + w * 32 + (lane >> 4) * 8;
    const float* src = W + ((size_t)(g * 1024 + jrow) << 10) + k;
    float4 v0 = *(const float4*)src;
    float4 v1 = *(const float4*)(src + 4);
    float vv[8] = {v0.x, v0.y, v0.z, v0.w, v1.x, v1.y, v1.z, v1.w};
    u16x8 hi, lo;
#pragma unroll
    for (int i = 0; i < 8; ++i) {
        u16 h = f2bf(vv[i]);
        hi[i] = h;
        lo[i] = f2bf(vv[i] - b2f(h));
    }
    size_t fr = ((((size_t)bid * 4 + kq) * 8 + w) * 2 + rh) * 2;
    *(u16x8*)(WF + fr * 512 + (size_t)lane * 8) = hi;
    *(u16x8*)(WF + (fr + 1) * 512 + (size_t)lane * 8) = lo;
}

// ---------------------------------------------------------------------------
// h0 fp32 [64 b][1024 j] -> per-GROUP fragment-major hi/lo slot (t=0 input).
// Group g owns batches g*16..+16; slot = 4 groups x 32768 u16 (64 KB each).
// Frag (kq,w,plane): lane l -> b_local = l&15, j = kq*256+w*32+(l>>4)*8+e.
// ---------------------------------------------------------------------------
__global__ __launch_bounds__(256) void h0frag(const float* __restrict__ h0,
                                              u16* __restrict__ slot) {
    int i = blockIdx.x * 256 + threadIdx.x;   // 8192 = 64 b x 128 j-groups
    int b = i >> 7, jg = i & 127;
    int j = jg << 3;
    const float* src = h0 + ((size_t)b << 10) + j;
    float4 v0 = *(const float4*)src;
    float4 v1 = *(const float4*)(src + 4);
    float vv[8] = {v0.x, v0.y, v0.z, v0.w, v1.x, v1.y, v1.z, v1.w};
    u16x8 hi, lo;
#pragma unroll
    for (int e = 0; e < 8; ++e) {
        u16 h = f2bf(vv[e]);
        hi[e] = h;
        lo[e] = f2bf(vv[e] - b2f(h));
    }
    int g = b >> 4, bl = b & 15;
    int kq = j >> 8, w = (j >> 5) & 7, tr = (j >> 3) & 3;
    int lane = tr * 16 + bl;
    size_t base = (size_t)g * 32768 + (size_t)((kq * 8 + w) * 2) * 512 + (size_t)lane * 8;
    *(u16x8*)(slot + base) = hi;
    *(u16x8*)(slot + base + 512) = lo;
}

// ---------------------------------------------------------------------------
// MFMA bf16 GEMM (A@B^T). XGT mode writes fp32 xgt[t][j*4+g][b] + bias.
// Staging now via global_load_lds (16B direct-to-LDS, no VGPR round trip).
// ---------------------------------------------------------------------------
template <bool TANH, bool XGT, typename OT>
__global__ __launch_bounds__(256) void gemm_mfma_bt(
    const u16* __restrict__ A0, const u16* __restrict__ A1,
    const u16* __restrict__ B, OT* __restrict__ C,
    int M, int N, int K, int KA0,
    const float* __restrict__ bias0, const float* __restrict__ bias1)
{
    __shared__ uint4 As4[512];
    __shared__ uint4 Bs4[512];
    u16* As = (u16*)As4;
    u16* Bs = (u16*)Bs4;
    const int tid = threadIdx.x;
    const int l = tid & 63;
    const int w = tid >> 6;
    const int wm = w >> 1, wn = w & 1;
    const int tc = l & 15, tr8 = (l >> 4) << 3;
    const int m0 = blockIdx.y << 7, n0 = blockIdx.x << 7;
    f32x4 acc[4][4] = {};

    for (int k0 = 0; k0 < K; k0 += 32) {
        const u16* Ap = (k0 < KA0) ? A0 : A1;
        const int koff = (k0 < KA0) ? k0 : k0 - KA0;
#pragma unroll
        for (int r = 0; r < 2; ++r) {
            int u = tid + (r << 8);
            int row = u >> 2, q = u & 3;
            size_t arow;
            if (XGT) {
                int rr = m0 + row;
                arow = (size_t)((rr & 63) * 128 + (rr >> 6));
            } else {
                arow = (size_t)(m0 + row);
            }
            GLOAD16(Ap + arow * KA0 + koff + (q << 3), &As4[u]);
            GLOAD16(B + (size_t)(n0 + row) * K + k0 + (q << 3), &Bs4[u]);
        }
        __syncthreads();
        bf16x8 bfr[4];
#pragma unroll
        for (int j = 0; j < 4; ++j)
            bfr[j] = *(const bf16x8*)(Bs + ((wn << 6) + (j << 4) + tc) * 32 + tr8);
#pragma unroll
        for (int i = 0; i < 4; ++i) {
            bf16x8 af = *(const bf16x8*)(As + ((wm << 6) + (i << 4) + tc) * 32 + tr8);
#pragma unroll
            for (int j = 0; j < 4; ++j)
                acc[i][j] = __builtin_amdgcn_mfma_f32_16x16x32_bf16(af, bfr[j], acc[i][j], 0, 0, 0);
        }
        __syncthreads();
    }
#pragma unroll
    for (int j = 0; j < 4; ++j) {
        const int col = n0 + (wn << 6) + (j << 4) + tc;
        const float bias = XGT ? (bias0[col] + bias1[col]) : 0.0f;
#pragma unroll
        for (int i = 0; i < 4; ++i) {
#pragma unroll
            for (int v = 0; v < 4; ++v) {
                int r = m0 + (wm << 6) + (i << 4) + ((l >> 4) << 2) + v;
                float val = acc[i][j][v];
                if (XGT) {
                    int newr = ((col & 1023) << 2) | (col >> 10);   // j*4+g
                    ((float*)C)[(size_t)(r >> 6) * 262144 + (size_t)newr * 64 + (r & 63)] = val + bias;
                } else {
                    if (TANH) val = tanhf(val);
                    stout(&C[(size_t)r * N + col], val);
                }
            }
        }
    }
}

// ---------------------------------------------------------------------------
// Persistent LSTM scan v8: batch-split groups. 256 blocks x 512 thr.
// 4 independent GROUPS of 64 blocks; group g owns batches g*16..+16.
// Block (ib = bid&63) owns 16 j x 4 gates = 64 W-rows for its 16 batches.
// Waves = 4 k-quarters x 2 row-halves; 32 W frags register-resident.
// h exchange: per-group 64 KB frag-major ring slot; cached frag reads,
// memory-side 8B atomic writes. GROUP-LOCAL hierarchical barrier
// (8 leaves x 8 -> root(8) -> gen -> leafgen). Math chain order identical
// to r11/r12 -> bit-identical output.
// ---------------------------------------------------------------------------
__global__ __launch_bounds__(512) void lstm_scan8(
    const float* __restrict__ xgt, const u16* __restrict__ WF,
    const float* __restrict__ c0,
    const u16* __restrict__ h0s, u16* __restrict__ ring,
    float* __restrict__ hT, float* __restrict__ cT,
    u16* __restrict__ lstm16, int* __restrict__ bar)
{
    __shared__ float red[4][64][17];             // 17.4 KB
    __shared__ __align__(8) u16 tileh[16][16];   // [b_local][j_local]
    __shared__ __align__(8) u16 tilel[16][16];
    const int tid = threadIdx.x;
    const int bid = blockIdx.x;
    const int g = bid >> 6;            // group 0..3
    const int ib = bid & 63;           // block in group
    const int kg = tid >> 6, l = tid & 63;
    const int kq = kg & 3, rh = kg >> 2;
    const int j0 = ib << 4;            // 16 j per block
    const int ebl = tid & 15;          // epilogue local batch
    const int ejl = tid >> 4;          // epilogue local j (tid<256)

    // W fragments -> registers (32 frags, held for all 128 steps)
    bf16x8 wfh[2][8], wfl[2][8];
#pragma unroll
    for (int rt = 0; rt < 2; ++rt) {
        const int R16 = ib * 4 + rh * 2 + rt;
        const int bw = R16 >> 1, rhw = R16 & 1;
#pragma unroll
        for (int w = 0; w < 8; ++w) {
            size_t fr = ((((size_t)bw * 4 + kq) * 8 + w) * 2 + rhw) * 2;
            wfh[rt][w] = *(const bf16x8*)(WF + fr * 512 + (size_t)l * 8);
            wfl[rt][w] = *(const bf16x8*)(WF + (fr + 1) * 512 + (size_t)l * 8);
        }
    }
    float cv = 0.0f;
    if (tid < 256) cv = c0[(size_t)(g * 16 + ebl) * 1024 + j0 + ejl];

    // xgt prefetch for t=0
    float xgv[4] = {};
    if (tid < 256) {
#pragma unroll
        for (int g2 = 0; g2 < 4; ++g2)
            xgv[g2] = xgt[(size_t)(((j0 + ejl) << 2) + g2) * 64 + g * 16 + ebl];
    }

    const int kqs = ib >> 4, ws = (ib >> 1) & 7;   // store-frag coords
    int* const gbar = bar + (g << 9);

    for (int t = 0; t < 128; ++t) {
        const u16* hin = ((t == 0) ? h0s : (ring + (size_t)(t - 1) * 131072)) + (size_t)g * 32768;
        u16* hout = ring + (size_t)t * 131072 + (size_t)g * 32768;

        f32x4 acc[2] = {};
        bf16x8 hbA[2], hbB[2];
#define LDW(HB, W)                                                                  \
        {                                                                           \
            size_t fb = (size_t)((kq * 8 + (W)) * 2) * 512 + (size_t)l * 8;         \
            HB[0] = *(const bf16x8*)(hin + fb);                                     \
            HB[1] = *(const bf16x8*)(hin + fb + 512);                               \
        }
        LDW(hbA, 0)
#pragma unroll
        for (int w = 0; w < 8; w += 2) {
            LDW(hbB, w + 1)
#pragma unroll
            for (int rt = 0; rt < 2; ++rt) {
                acc[rt] = __builtin_amdgcn_mfma_f32_16x16x32_bf16(wfh[rt][w], hbA[0], acc[rt], 0, 0, 0);
                acc[rt] = __builtin_amdgcn_mfma_f32_16x16x32_bf16(wfh[rt][w], hbA[1], acc[rt], 0, 0, 0);
                acc[rt] = __builtin_amdgcn_mfma_f32_16x16x32_bf16(wfl[rt][w], hbA[0], acc[rt], 0, 0, 0);
            }
            if (w + 2 < 8) LDW(hbA, w + 2)
#pragma unroll
            for (int rt = 0; rt < 2; ++rt) {
                acc[rt] = __builtin_amdgcn_mfma_f32_16x16x32_bf16(wfh[rt][w + 1], hbB[0], acc[rt], 0, 0, 0);
                acc[rt] = __builtin_amdgcn_mfma_f32_16x16x32_bf16(wfh[rt][w + 1], hbB[1], acc[rt], 0, 0, 0);
                acc[rt] = __builtin_amdgcn_mfma_f32_16x16x32_bf16(wfl[rt][w + 1], hbB[0], acc[rt], 0, 0, 0);
            }
        }
#undef LDW

#pragma unroll
        for (int rt = 0; rt < 2; ++rt)
#pragma unroll
            for (int v = 0; v < 4; ++v)
                red[kq][(rh << 5) + (rt << 4) + ((l >> 4) << 2) + v][l & 15] = acc[rt][v];
        __syncthreads();

        // epilogue (tid<256): one (b_local=ebl, j_local=ejl) per thread
        if (tid < 256) {
            float gate[4];
#pragma unroll
            for (int g2 = 0; g2 < 4; ++g2) {
                int rr = (ejl << 2) + g2;
                gate[g2] = red[0][rr][ebl] + red[1][rr][ebl] +
                           red[2][rr][ebl] + red[3][rr][ebl] + xgv[g2];
            }
            float ii = sigmoidf_(gate[0]);
            float ff = sigmoidf_(gate[1]);
            float gg = tanhf(gate[2]);
            float oo = sigmoidf_(gate[3]);
            float cn = ff * cv + ii * gg;
            float hn = oo * tanhf(cn);
            cv = cn;
            u16 hh = f2bf(hn);
            tileh[ebl][ejl] = hh;
            tilel[ebl][ejl] = f2bf(hn - b2f(hh));
            if (t == 127) {
                hT[(size_t)(g * 16 + ebl) * 1024 + j0 + ejl] = hn;
                cT[(size_t)(g * 16 + ebl) * 1024 + j0 + ejl] = cn;
            }
        }
        __syncthreads();

        // store phase: group ring slot (8B atomics, frag layout) + lstm16
        if (tid < 128) {
            const int plane = tid >> 6, rem = tid & 63;
            const int b2 = rem >> 2, half = (rem >> 1) & 1, qq = rem & 1;
            const int lane = ((ib & 1) * 2 + half) * 16 + b2;
            const u16* tp = plane ? &tilel[b2][half * 8 + qq * 4] : &tileh[b2][half * 8 + qq * 4];
            size_t a16 = (size_t)(((kqs * 8 + ws) * 2 + plane)) * 512 + (size_t)lane * 8 + qq * 4;
            astore((u64t*)(hout + a16), *(const u64t*)tp);
            if (plane == 0) {
                int qj = rem & 3;
                *(u64t*)(lstm16 + ((size_t)(g * 16 + b2) * 128 + t) * 1024 + j0 + qj * 4) =
                    *(const u64t*)&tileh[b2][qj * 4];
            }
        }

        // prefetch next step's xgt (independent of h) before the barrier
        if (t < 127) {
            if (tid < 256) {
#pragma unroll
                for (int g2 = 0; g2 < 4; ++g2)
                    xgv[g2] = xgt[(size_t)(t + 1) * 262144 +
                                  (size_t)(((j0 + ejl) << 2) + g2) * 64 + g * 16 + ebl];
            }
            __syncthreads();   // drains vmem: ring stores memory-side-visible
            if (tid == 0) {
                const int leaf = ib & 7;
                int a = afetchadd(&gbar[leaf * 16]);
                if ((a & 7) == 7) {
                    int r = afetchadd(&gbar[128]);
                    if ((r & 7) == 7) astore32(&gbar[136], t + 1);
                    while (aload32(&gbar[136]) < t + 1) __builtin_amdgcn_s_sleep(2);
                    astore32(&gbar[144 + leaf * 16], t + 1);
                } else {
                    while (aload32(&gbar[144 + leaf * 16]) < t + 1)
                        __builtin_amdgcn_s_sleep(2);
                }
            }
            __syncthreads();
        }
    }
}

// ---------------------------------------------------------------------------
// scores[b] = q[b] @ ctx[b]^T  via split-precision MFMA (fp32-equivalent).
// ---------------------------------------------------------------------------
__global__ __launch_bounds__(256) void scores_mfma(
    const float* __restrict__ q, const float* __restrict__ ctx,
    float* __restrict__ C)
{
    __shared__ u16 Ahi[4096], Alo[4096], Bhi[4096], Blo[4096];
    const int tid = threadIdx.x;
    const int l = tid & 63, w = tid >> 6;
    const int wm = w >> 1, wn = w & 1;
    const int tc = l & 15, tr8 = (l >> 4) << 3;
    const int b = blockIdx.z, n0 = blockIdx.x << 7;
    const float* A = q + (size_t)b * 131072;
    const float* B = ctx + (size_t)b * 262144;
    f32x4 acc[4][4] = {};

    for (int k0 = 0; k0 < 1024; k0 += 32) {
#pragma unroll
        for (int r = 0; r < 4; ++r) {
            int flat = r * 256 + tid;
            int row = flat >> 3, kq = (flat & 7) << 2;
            int o = row * 32 + kq;
            float4 va = *(const float4*)(A + (size_t)row * 1024 + k0 + kq);
            u16 a0 = f2bf(va.x), a1 = f2bf(va.y), a2 = f2bf(va.z), a3 = f2bf(va.w);
            *(ushort4*)&Ahi[o] = (ushort4){a0, a1, a2, a3};
            *(ushort4*)&Alo[o] = (ushort4){f2bf(va.x - b2f(a0)), f2bf(va.y - b2f(a1)),
                                           f2bf(va.z - b2f(a2)), f2bf(va.w - b2f(a3))};
            float4 vb = *(const float4*)(B + (size_t)(n0 + row) * 1024 + k0 + kq);
            u16 g0 = f2bf(vb.x), g1 = f2bf(vb.y), g2 = f2bf(vb.z), g3 = f2bf(vb.w);
            *(ushort4*)&Bhi[o] = (ushort4){g0, g1, g2, g3};
            *(ushort4*)&Blo[o] = (ushort4){f2bf(vb.x - b2f(g0)), f2bf(vb.y - b2f(g1)),
                                           f2bf(vb.z - b2f(g2)), f2bf(vb.w - b2f(g3))};
        }
        __syncthreads();
        bf16x8 bh[4], bl[4];
#pragma unroll
        for (int j = 0; j < 4; ++j) {
            int o = ((wn << 6) + (j << 4) + tc) * 32 + tr8;
            bh[j] = *(const bf16x8*)(Bhi + o);
            bl[j] = *(const bf16x8*)(Blo + o);
        }
#pragma unroll
        for (int i = 0; i < 4; ++i) {
            int o = ((wm << 6) + (i << 4) + tc) * 32 + tr8;
            bf16x8 ah = *(const bf16x8*)(Ahi + o);
            bf16x8 al = *(const bf16x8*)(Alo + o);
#pragma unroll
            for (int j = 0; j < 4; ++j) {
                acc[i][j] = __builtin_amdgcn_mfma_f32_16x16x32_bf16(ah, bh[j], acc[i][j], 0, 0, 0);
                acc[i][j] = __builtin_amdgcn_mfma_f32_16x16x32_bf16(ah, bl[j], acc[i][j], 0, 0, 0);
                acc[i][j] = __builtin_amdgcn_mfma_f32_16x16x32_bf16(al, bh[j], acc[i][j], 0, 0, 0);
            }
        }
        __syncthreads();
    }
#pragma unroll
    for (int j = 0; j < 4; ++j) {
        int col = n0 + (wn << 6) + (j << 4) + tc;
#pragma unroll
        for (int i = 0; i < 4; ++i)
#pragma unroll
            for (int v = 0; v < 4; ++v) {
                int r = (wm << 6) + (i << 4) + ((l >> 4) << 2) + v;
                C[(size_t)b * 32768 + (size_t)r * 256 + col] = acc[i][j][v];
            }
    }
}

// ---------------------------------------------------------------------------
// Masked softmax over S=256; fp32 scores -> bf16 attn.
// ---------------------------------------------------------------------------
__global__ __launch_bounds__(256) void softmax_mask16(
    const float* __restrict__ scores, const int* __restrict__ src_len,
    u16* __restrict__ attn16)
{
    __shared__ float red[4];
    const int b = blockIdx.y, t = blockIdx.x, s = threadIdx.x;
    const float* row = scores + ((long)b * TT + t) * SS;
    const int L = src_len[b];
    float v = (s < L) ? row[s] : -INFINITY;
    float m = v;
#pragma unroll
    for (int o = 32; o >= 1; o >>= 1) m = fmaxf(m, __shfl_xor(m, o));
    if ((s & 63) == 0) red[s >> 6] = m;
    __syncthreads();
    m = fmaxf(fmaxf(red[0], red[1]), fmaxf(red[2], red[3]));
    __syncthreads();
    float e = (s < L) ? expf(v - m) : 0.0f;
    float sum = e;
#pragma unroll
    for (int o = 32; o >= 1; o >>= 1) sum += __shfl_xor(sum, o);
    if ((s & 63) == 0) red[s >> 6] = sum;
    __syncthreads();
    sum = red[0] + red[1] + red[2] + red[3];
    attn16[((long)b * TT + t) * SS + s] = f2bf(e / sum);
}

// ---------------------------------------------------------------------------
// context[b] = attn[b] @ ctx[b]  via bf16 MFMA (B transposed in-LDS).
// ---------------------------------------------------------------------------
__global__ __launch_bounds__(256) void ctxattn_mfma(
    const u16* __restrict__ attn16, const float* __restrict__ ctx,
    u16* __restrict__ ctxout16)
{
    __shared__ u16 As[4096];
    __shared__ u16 Bs[128][40];
    const int tid = threadIdx.x;
    const int l = tid & 63, w = tid >> 6;
    const int wm = w >> 1, wn = w & 1;
    const int tc = l & 15, tr8 = (l >> 4) << 3;
    const int b = blockIdx.z, n0 = blockIdx.x << 7;
    f32x4 acc[4][4] = {};

    for (int k0 = 0; k0 < 256; k0 += 32) {
        {
            int row = tid >> 1, off = (tid & 1) << 4;
            const u16* src = attn16 + (size_t)b * 32768 + (size_t)row * 256 + k0 + off;
            *(uint4*)&As[row * 32 + off] = *(const uint4*)src;
            *(uint4*)&As[row * 32 + off + 8] = *(const uint4*)(src + 8);
        }
#pragma unroll
        for (int p = 0; p < 4; ++p) {
            int flat = p * 256 + tid;
            int s = flat >> 5, hc = flat & 31;
            float4 v = *(const float4*)(ctx + (size_t)b * 262144 +
                                        (size_t)(k0 + s) * 1024 + n0 + (hc << 2));
            Bs[(hc << 2) + 0][s] = f2bf(v.x);
            Bs[(hc << 2) + 1][s] = f2bf(v.y);
            Bs[(hc << 2) + 2][s] = f2bf(v.z);
            Bs[(hc << 2) + 3][s] = f2bf(v.w);
        }
        __syncthreads();
        bf16x8 bfr[4];
#pragma unroll
        for (int j = 0; j < 4; ++j)
            bfr[j] = *(const bf16x8*)&Bs[(wn << 6) + (j << 4) + tc][tr8];
#pragma unroll
        for (int i = 0; i < 4; ++i) {
            bf16x8 af = *(const bf16x8*)(As + ((wm << 6) + (i << 4) + tc) * 32 + tr8);
#pragma unroll
            for (int j = 0; j < 4; ++j)
                acc[i][j] = __builtin_amdgcn_mfma_f32_16x16x32_bf16(af, bfr[j], acc[i][j], 0, 0, 0);
        }
        __syncthreads();
    }
#pragma unroll
    for (int j = 0; j < 4; ++j) {
        int col = n0 + (wn << 6) + (j << 4) + tc;
#pragma unroll
        for (int i = 0; i < 4; ++i)
#pragma unroll
            for (int v = 0; v < 4; ++v) {
                int r = (wm << 6) + (i << 4) + ((l >> 4) << 2) + v;
                ctxout16[((size_t)b * 128 + r) * 1024 + col] = f2bf(acc[i][j][v]);
            }
    }
}

// ---------------------------------------------------------------------------
extern "C" void kernel_launch(void* const* d_in, const int* in_sizes, int n_in,
                              void* d_out, int out_size, void* d_ws, size_t ws_size,
                              hipStream_t stream)
{
    const float* trg_emb = (const float*)d_in[0];
    const float* h0      = (const float*)d_in[1];
    const float* c0      = (const float*)d_in[2];
    const float* ctx     = (const float*)d_in[3];
    const int*   src_len = (const int*)d_in[4];
    const float* W_ih    = (const float*)d_in[5];
    const float* W_hh    = (const float*)d_in[6];
    const float* b_ih    = (const float*)d_in[7];
    const float* b_hh    = (const float*)d_in[8];
    const float* W_in    = (const float*)d_in[9];
    const float* W_out   = (const float*)d_in[10];

    float* out = (float*)d_out;
    float* h_tilde = out;                          // [B,T,H]
    float* hT = out + (size_t)BB * TT * HHH;       // [1,B,H]
    float* cT = hT + (size_t)BB * HHH;             // [1,B,H]

    char* w = (char*)d_ws;
    auto take = [&](size_t bytes) { void* p = w; w += (bytes + 255) & ~(size_t)255; return p; };
    // ring (128 slots x 256 KB = 33.55 MB) aliases trg16+Wih16+spare (safe:
    // ring written only inside lstm_scan8, after the xgt GEMM — stream order).
    char* base0 = w;
    u16* trg16  = (u16*)take(8388608ull * 2);      // 16.78 MB
    u16* Wih16  = (u16*)take(4194304ull * 2);      //  8.39 MB
    take(8388608ull);                              //  8.39 MB ring tail spare
    u16* ring   = (u16*)base0;                     // 33.55 MB total
    u16* h0s    = (u16*)take(262144ull);           // 4-group frag slot for t=0
    u16* Win16  = (u16*)take(1048576ull * 2);
    u16* Wout16 = (u16*)take(2097152ull * 2);
    u16* lstm16 = (u16*)take(8388608ull * 2);
    u16* WF     = (u16*)take(16777216ull);         // W fragment layout
    int* bar    = (int*)take(8192);
    char* regionB = w;
    float* xgt = (float*)take(33554432ull * 4);    // [t][4H r=j*4+g][B] fp32
    float* q        = (float*)regionB;                          // 33.55 MB
    float* scores   = (float*)(regionB + 33554432ull);          //  8.39 MB
    u16*   attn16   = (u16*)(regionB + 41943040ull);            //  4.19 MB
    u16*   ctxout16 = (u16*)(regionB + 46137344ull);            // 16.78 MB

    // barrier counters must start at 0 every call
    hipMemsetAsync(bar, 0, 8192, stream);

    // prep (independent, parallel)
    f32_to_bf16<<<4096, 256, 0, stream>>>(trg_emb, trg16, 8388608);
    f32_to_bf16<<<2048, 256, 0, stream>>>(W_ih, Wih16, 4194304);
    f32_to_bf16<<<512, 256, 0, stream>>>(W_in, Win16, 1048576);
    f32_to_bf16<<<1024, 256, 0, stream>>>(W_out, Wout16, 2097152);
    wfrag_build<<<dim3(8, 4, 128), 128, 0, stream>>>(W_hh, WF);
    h0frag<<<32, 256, 0, stream>>>(h0, h0s);

    // x_gates = trg_emb @ W_ih^T + (b_ih+b_hh) -> fp32 xgt[t][j*4+g][b]
    gemm_mfma_bt<false, true, float><<<dim3(32, 64), 256, 0, stream>>>(
        trg16, trg16, Wih16, xgt, 8192, 4096, 1024, 1024, b_ih, b_hh);

    // persistent LSTM scan (single launch; writes lstm16, hT, cT)
    lstm_scan8<<<256, 512, 0, stream>>>(xgt, WF, c0, h0s, ring,
                                        hT, cT, lstm16, bar);

    // q = lstm_out @ W_in^T (bf16 MFMA, fp32 out)
    gemm_mfma_bt<false, false, float><<<dim3(8, 64), 256, 0, stream>>>(
        lstm16, lstm16, Win16, q, 8192, 1024, 1024, 1024, nullptr, nullptr);

    // scores[b] = q[b] @ ctx[b]^T (split-precision MFMA, fp32-equivalent)
    scores_mfma<<<dim3(2, 1, 64), 256, 0, stream>>>(q, ctx, scores);

    // masked softmax -> bf16 attention weights
    softmax_mask16<<<dim3(TT, BB, 1), 256, 0, stream>>>(scores, src_len, attn16);

    // context[b] = attn[b] @ ctx[b] (bf16 MFMA, bf16 out)
    ctxattn_mfma<<<dim3(8, 1, 64), 256, 0, stream>>>(attn16, ctx, ctxout16);

    // h_tilde = tanh([context, lstm_out] @ W_out^T)
    gemm_mfma_bt<true, false, float><<<dim3(8, 64), 256, 0, stream>>>(
        ctxout16, lstm16, Wout16, h_tilde, 8192, 1024, 2048, 1024, nullptr, nullptr);
}